// Round 10
// baseline (460.404 us; speedup 1.0000x reference)
//
#include <hip/hip_runtime.h>
#include <hip/hip_bf16.h>
#include <math.h>

#define BSZ 4
#define VN 2048
#define SS 7
#define KNB 10

typedef __attribute__((ext_vector_type(8))) short short8;
typedef __attribute__((ext_vector_type(4))) float f32x4;
typedef __attribute__((address_space(1))) const void gcvoid;
typedef __attribute__((address_space(3))) void lvoid;

__device__ inline ushort f2bf(float x) {
    __hip_bfloat16 h = __float2bfloat16(x);
    return *(ushort*)&h;
}

__device__ inline void gl2lds16(const ushort* g, ushort* l) {
    __builtin_amdgcn_global_load_lds((gcvoid*)g, (lvoid*)l, 16, 0, 0);
}

__device__ inline unsigned fenc(float f) {
    unsigned b = __float_as_uint(f);
    return (b & 0x80000000u) ? ~b : (b | 0x80000000u);
}
__device__ inline float fdec(unsigned e) {
    unsigned b = (e & 0x80000000u) ? (e & 0x7FFFFFFFu) : ~e;
    return __uint_as_float(b);
}

#define INS(dq, iq, dd, jj) { bool lt_ = (dd) < (dq); \
    float dmn_ = lt_ ? (dd) : (dq); float dmx_ = lt_ ? (dq) : (dd); \
    int imn_ = lt_ ? (jj) : (iq); int imx_ = lt_ ? (iq) : (jj); \
    (dq) = dmn_; (iq) = imn_; (dd) = dmx_; (jj) = imx_; }

// ---------------------------------------------------------------- prep (device fn; part of front_uber)
#define PB0 8960L
#define PB1 24320L
#define PB2 958208L
#define PB3 1220352L
#define PREP_BLOCKS 4767        // PB3 / 256

__device__ void prep_dev(int gb,
                         const float* __restrict__ d0, const float* __restrict__ d1,
                         const float* __restrict__ d2, const float* __restrict__ d3,
                         const float* __restrict__ d4,
                         float* __restrict__ s0, float* __restrict__ s1,
                         float* __restrict__ s2, float* __restrict__ s3, float* __restrict__ s4,
                         const float* __restrict__ wc3, float* __restrict__ wc3t,
                         const float* __restrict__ wc1, ushort* __restrict__ wc1b,
                         const float* __restrict__ wc2, ushort* __restrict__ wc2b) {
    long i = gb * 256L + threadIdx.x;
    if (i < PB0) {
        const float* src; float* dst; int C, c;
        if (i < 896)        { src = d0; dst = s0; C = 896;  c = (int)i; }
        else if (i < 1792)  { src = d1; dst = s1; C = 896;  c = (int)i - 896; }
        else if (i < 3584)  { src = d2; dst = s2; C = 1792; c = (int)i - 1792; }
        else if (i < 5376)  { src = d3; dst = s3; C = 1792; c = (int)i - 3584; }
        else                { src = d4; dst = s4; C = 3584; c = (int)i - 5376; }
        float a = src[c], b = src[C + c], e = src[2 * C + c];
        float den = fmaxf(sqrtf(a * a + b * b + e * e), 1e-12f);
        dst[c] = a / den; dst[C + c] = b / den; dst[2 * C + c] = e / den;
    } else if (i < PB1) {
        long j = i - PB0;
        int o = (int)(j / 512), k = (int)(j % 512);
        wc3t[(long)k * 30 + o] = wc3[j];
    } else if (i < PB2) {
        long j = i - PB1;
        int c = (int)(j % 1824);
        long r = j / 1824;
        wc1b[j] = f2bf(c < 1808 ? wc1[r * 1808 + c] : 0.f);
    } else if (i < PB3) {
        long j = i - PB2;
        wc2b[j] = f2bf(wc2[j]);
    }
}

// ---------------------------------------------------------------- weight transpose (device fn; part of front_uber)
__device__ void wt_trans_dev(int gb, float* tilef,
                             const float* __restrict__ w1, const float* __restrict__ w2,
                             const float* __restrict__ w3, const float* __restrict__ w4,
                             ushort* __restrict__ o1, ushort* __restrict__ o2,
                             ushort* __restrict__ o3, ushort* __restrict__ o4) {
    const float* w; ushort* o; int K, N, t;
    if (gb < 128)      { w = w1; o = o1; K = 128; N = 1024; t = gb; }
    else if (gb < 384) { w = w2; o = o2; K = 128; N = 2048; t = gb - 128; }
    else if (gb < 896) { w = w3; o = o3; K = 256; N = 2048; t = gb - 384; }
    else               { w = w4; o = o4; K = 256; N = 4096; t = gb - 896; }
    int tn = t % (N / 32), tk = t / (N / 32);
    int n0 = tn * 32, k0 = tk * 32;
    int tx = threadIdx.x % 32, ty = threadIdx.x / 32;
#pragma unroll
    for (int r = 0; r < 32; r += 8)
        tilef[(ty + r) * 33 + tx] = w[(long)(k0 + ty + r) * N + n0 + tx];
    __syncthreads();
#pragma unroll
    for (int r = 0; r < 32; r += 8)
        o[(long)(n0 + ty + r) * K + k0 + tx] = f2bf(tilef[tx * 33 + ty + r]);
}

// ---------------------------------------------------------------- knn part (exact fp32, 64-source chunks)
// Only the 2048x2048 pass is computed: pooled point sets vp1/vp2 are PREFIXES of vertices
// (verts[:, :512], verts[:, :128]), so their partial lists are sub-slices of the big run.
// per target, per 64-source chunk: 2 sorted 10-lists (sublists of 32 sources, ascending index ranges)
// pd[ ((b*2048 + i)*32 + ch)*20 + l*10 + q ] == row (b*2048+i), list c=2*ch+l at (row*64+c)*10
#define KTOT  5242880L

__device__ void knn_part_dev(const float* __restrict__ verts, int T, int nch,
                             int tile, int b, int ch,
                             float* __restrict__ pd, ushort* __restrict__ pi,
                             float4* __restrict__ s4) {
    const float* vb = verts + (long)b * VN * 3;
    int j0 = ch * 64;
    for (int j = threadIdx.x; j < 64; j += 256) {
        float x = vb[(j0 + j) * 3 + 0];
        float y = vb[(j0 + j) * 3 + 1];
        float z = vb[(j0 + j) * 3 + 2];
        s4[j] = make_float4(x, y, z, x * x + y * y + z * z);
    }
    __syncthreads();
    int i = tile * 256 + (int)threadIdx.x;
    if (i >= T) return;
    float px = vb[i * 3], py = vb[i * 3 + 1], pz = vb[i * 3 + 2];
    float d0[10], d1[10];
    int id0[10], id1[10];
#pragma unroll
    for (int q = 0; q < 10; q++) {
        d0[q] = 1e30f; d1[q] = 1e30f;
        id0[q] = 0; id1[q] = 0;
    }
    for (int j = 0; j < 32; j++) {
        float4 sA = s4[j];
        float4 sB = s4[32 + j];
        float dA = fmaf(-2.f, px * sA.x + py * sA.y + pz * sA.z, sA.w);
        float dB = fmaf(-2.f, px * sB.x + py * sB.y + pz * sB.z, sB.w);
        int jA = j0 + j, jB = j0 + 32 + j;
        dA = (jA == i) ? 1e30f : dA;
        dB = (jB == i) ? 1e30f : dB;
#pragma unroll
        for (int q = 0; q < 10; q++) { INS(d0[q], id0[q], dA, jA); }
#pragma unroll
        for (int q = 0; q < 10; q++) { INS(d1[q], id1[q], dB, jB); }
    }
    long base = ((long)(b * T + i) * nch + ch) * 20;
    // vectorized stores: base is a multiple of 20 floats (80B) -> list0 16B-aligned, list1 (+40B) 8B-aligned
    *(float4*)(pd + base)      = make_float4(d0[0], d0[1], d0[2], d0[3]);
    *(float4*)(pd + base + 4)  = make_float4(d0[4], d0[5], d0[6], d0[7]);
    *(float2*)(pd + base + 8)  = make_float2(d0[8], d0[9]);
    *(float2*)(pd + base + 10) = make_float2(d1[0], d1[1]);
    *(float2*)(pd + base + 12) = make_float2(d1[2], d1[3]);
    *(float2*)(pd + base + 14) = make_float2(d1[4], d1[5]);
    *(float2*)(pd + base + 16) = make_float2(d1[6], d1[7]);
    *(float2*)(pd + base + 18) = make_float2(d1[8], d1[9]);
    // index pairs packed little-endian u16|u16<<16 == the u32 words the merge reads
    uint* pu = (uint*)(pi + base);
#pragma unroll
    for (int q = 0; q < 5; q++)
        pu[q] = (uint)(ushort)id0[2 * q] | ((uint)(ushort)id0[2 * q + 1] << 16);
#pragma unroll
    for (int q = 0; q < 5; q++)
        pu[5 + q] = (uint)(ushort)id1[2 * q] | ((uint)(ushort)id1[2 * q + 1] << 16);
}

__device__ void nearest_dev(const float* __restrict__ verts, int SN, int* __restrict__ out,
                            int gl, float4* __restrict__ s4) {
    int t = gl * 256 + (int)threadIdx.x;
    int b = t / VN;
    const float* vb = verts + (long)b * VN * 3;
    for (int j = threadIdx.x; j < SN; j += 256) {
        float x = vb[j * 3], y = vb[j * 3 + 1], z = vb[j * 3 + 2];
        s4[j] = make_float4(x, y, z, x * x + y * y + z * z);
    }
    __syncthreads();
    int i = t % VN;
    float px = vb[i * 3], py = vb[i * 3 + 1], pz = vb[i * 3 + 2];
    int h = SN / 2;
    float b0 = 1e30f, b1 = 1e30f; int i0 = 0, i1 = 0;
    for (int j = 0; j < h; j++) {
        float4 sA = s4[j];
        float4 sB = s4[h + j];
        float dA = fmaf(-2.f, px * sA.x + py * sA.y + pz * sA.z, sA.w);
        float dB = fmaf(-2.f, px * sB.x + py * sB.y + pz * sB.z, sB.w);
        bool lA = dA < b0; b0 = lA ? dA : b0; i0 = lA ? j : i0;
        bool lB = dB < b1; b1 = lB ? dB : b1; i1 = lB ? (h + j) : i1;
    }
    out[t] = (b1 < b0) ? i1 : i0;
}

// ---------------------------------------------------------------- front uber: knn part + nearest + prep + weight transpose
//  [0,1024)        knn big: 8 tiles x (4 b x 32 ch)   2048x2048
//  [1024,1056)     nearest n1 (512 sources)
//  [1056,1088)     nearest n2 (128 sources)
//  [1088,5855)     prep (4767 blocks)
//  [5855,7775)     weight transpose (1920 blocks)
__global__ __launch_bounds__(256) void front_uber(const float* __restrict__ verts,
                                                  float* __restrict__ pd, ushort* __restrict__ pi,
                                                  int* __restrict__ n1, int* __restrict__ n2,
                                                  const float* __restrict__ d0, const float* __restrict__ d1,
                                                  const float* __restrict__ d2, const float* __restrict__ d3,
                                                  const float* __restrict__ d4,
                                                  float* __restrict__ s0, float* __restrict__ s1,
                                                  float* __restrict__ s2, float* __restrict__ s3,
                                                  float* __restrict__ s4v,
                                                  const float* __restrict__ wc3, float* __restrict__ wc3t,
                                                  const float* __restrict__ wc1, ushort* __restrict__ wc1b,
                                                  const float* __restrict__ wc2, ushort* __restrict__ wc2b,
                                                  const float* __restrict__ w1, const float* __restrict__ w2,
                                                  const float* __restrict__ w3, const float* __restrict__ w4,
                                                  ushort* __restrict__ o1, ushort* __restrict__ o2,
                                                  ushort* __restrict__ o3, ushort* __restrict__ o4) {
    __shared__ float4 smem[512];        // knn/nearest: float4[512]; trans: float[32][33] alias
    int gb = blockIdx.x;
    if (gb < 1024) {
        int tile = gb & 7, bc = gb >> 3;
        knn_part_dev(verts, 2048, 32, tile, bc >> 5, bc & 31, pd, pi, smem);
    } else if (gb < 1056) {
        nearest_dev(verts, 512, n1, gb - 1024, smem);
    } else if (gb < 1088) {
        nearest_dev(verts, 128, n2, gb - 1056, smem);
    } else if (gb < 1088 + PREP_BLOCKS) {
        prep_dev(gb - 1088, d0, d1, d2, d3, d4, s0, s1, s2, s3, s4v,
                 wc3, wc3t, wc1, wc1b, wc2, wc2b);
    } else {
        wt_trans_dev(gb - (1088 + PREP_BLOCKS), (float*)smem, w1, w2, w3, w4, o1, o2, o3, o4);
    }
}

// ---------------------------------------------------------------- knn selection: lane-per-list tournament
template <int G>
__device__ void knn_sel_dev(const float* __restrict__ pd, const ushort* __restrict__ pi,
                            int blk, int Tsub, int* __restrict__ out,
                            int* __restrict__ outp, int Tp) {
    typedef unsigned long long u64;
    constexpr int TPB = 256 / G;        // targets per block
    int tid = threadIdx.x;
    long t = (long)blk * TPB + (tid / G);
    int c = tid % G;
    int bb = (int)(t / Tsub), ii = (int)(t % Tsub);
    long row = (long)bb * 2048 + ii;
    long base = (row * 64 + c) * 10;
    const float2* pf = (const float2*)(pd + base);   // 40B stride -> 8B aligned
    const uint*   pu = (const uint*)(pi + base);     // 20B stride -> 4B aligned
    float2 f0 = pf[0], f1 = pf[1], f2 = pf[2], f3 = pf[3], f4 = pf[4];
    uint   u0 = pu[0], u1 = pu[1], u2 = pu[2], u3 = pu[3], u4 = pu[4];
    u64 k0 = ((u64)fenc(f0.x) << 32) | (u0 & 0xFFFFu);
    u64 k1 = ((u64)fenc(f0.y) << 32) | (u0 >> 16);
    u64 k2 = ((u64)fenc(f1.x) << 32) | (u1 & 0xFFFFu);
    u64 k3 = ((u64)fenc(f1.y) << 32) | (u1 >> 16);
    u64 k4 = ((u64)fenc(f2.x) << 32) | (u2 & 0xFFFFu);
    u64 k5 = ((u64)fenc(f2.y) << 32) | (u2 >> 16);
    u64 k6 = ((u64)fenc(f3.x) << 32) | (u3 & 0xFFFFu);
    u64 k7 = ((u64)fenc(f3.y) << 32) | (u3 >> 16);
    u64 k8 = ((u64)fenc(f4.x) << 32) | (u4 & 0xFFFFu);
    u64 k9 = ((u64)fenc(f4.y) << 32) | (u4 >> 16);
    bool wp = (outp != nullptr) && (ii < Tp);
#pragma unroll
    for (int q = 0; q < 10; q++) {
        u64 m = k0;
#pragma unroll
        for (int s = 1; s < G; s <<= 1) {
            u64 o = (u64)__shfl_xor((long long)m, s);
            m = (o < m) ? o : m;
        }
        if (c == 0) {
            int idx = (int)(unsigned)(m & 0xFFFFFFFFull);
            out[t * 10 + q] = idx;
            if (wp && q < 4) outp[((long)bb * Tp + ii) * 4 + q] = idx;
        }
        if (k0 == m) {
            k0 = k1; k1 = k2; k2 = k3; k3 = k4; k4 = k5;
            k5 = k6; k6 = k7; k7 = k8; k8 = k9;
            k9 = 0xFFFFFFFFFFFFFFFFull;
        }
    }
}

// grid: [0,2048) big (8192 t, 64 lists, 4 t/blk) | [2048,2176) mid (2048 t, 16 lists, 16 t/blk)
//       | [2176,2184) small (512 t, 4 lists, 64 t/blk)
__global__ __launch_bounds__(256) void knn_merge_uber(const float* __restrict__ pd, const ushort* __restrict__ pi,
                                                      int* __restrict__ nb, int* __restrict__ nb1,
                                                      int* __restrict__ nb2, int* __restrict__ nbp1,
                                                      int* __restrict__ nbp2) {
    int gb = blockIdx.x;
    if (gb < 2048)      knn_sel_dev<64>(pd, pi, gb, 2048, nb, nbp1, 512);
    else if (gb < 2176) knn_sel_dev<16>(pd, pi, gb - 2048, 512, nb1, nbp2, 128);
    else                knn_sel_dev<4>(pd, pi, gb - 2176, 128, nb2, nullptr, 1);
}

// ---------------------------------------------------------------- conv_surface (fp32 + bf16 out)
__global__ void conv_surface_kernel(const float* __restrict__ verts, const int* __restrict__ nb,
                                    const float* __restrict__ sd, float* __restrict__ fm0,
                                    ushort* __restrict__ fm0b) {
    int bv = blockIdx.x;
    int b = bv / VN, v = bv % VN;
    __shared__ float snd[KNB][3];
    int tid = threadIdx.x;
    if (tid < KNB) {
        int nj = nb[(long)bv * KNB + tid];
        const float* vb = verts + (long)b * VN * 3;
        float dx = vb[nj * 3] - vb[v * 3];
        float dy = vb[nj * 3 + 1] - vb[v * 3 + 1];
        float dz = vb[nj * 3 + 2] - vb[v * 3 + 2];
        float den = fmaxf(sqrtf(dx * dx + dy * dy + dz * dz), 1e-12f);
        snd[tid][0] = dx / den; snd[tid][1] = dy / den; snd[tid][2] = dz / den;
    }
    __syncthreads();
    int c = tid;
    float acc = 0.f;
    for (int s = 0; s < SS; s++) {
        int col = s * 128 + c;
        float s0 = sd[col], s1 = sd[896 + col], s2 = sd[2 * 896 + col];
        float m = 0.f;
#pragma unroll
        for (int n = 0; n < KNB; n++) {
            float dot = snd[n][0] * s0 + snd[n][1] * s1 + snd[n][2] * s2;
            m = fmaxf(m, dot);
        }
        acc += m;
    }
    fm0[(long)bv * 128 + c] = acc;
    fm0b[(long)bv * 128 + c] = f2bf(acc);
}

// ---------------------------------------------------------------- conv_layer act (+opt fg max)
__global__ void conv_act_kernel(const float* __restrict__ verts, const int* __restrict__ nb,
                                const float* __restrict__ sd, const float* __restrict__ fo,
                                float* __restrict__ out, unsigned* __restrict__ fgmax,
                                int Vl, int outC) {
    int bv = blockIdx.x;
    int b = bv / Vl, v = bv % Vl;
    __shared__ float snd[KNB][3];
    __shared__ int srow[KNB];
    int tid = threadIdx.x;
    if (tid < KNB) {
        int nj = nb[(long)bv * KNB + tid];
        srow[tid] = b * Vl + nj;
        const float* vb = verts + (long)b * VN * 3;
        float dx = vb[nj * 3] - vb[v * 3];
        float dy = vb[nj * 3 + 1] - vb[v * 3 + 1];
        float dz = vb[nj * 3 + 2] - vb[v * 3 + 2];
        float den = fmaxf(sqrtf(dx * dx + dy * dy + dz * dz), 1e-12f);
        snd[tid][0] = dx / den; snd[tid][1] = dy / den; snd[tid][2] = dz / den;
    }
    __syncthreads();
    int c = tid;
    int SC = SS * outC;
    int foN = SC + outC;
    float acc = fo[(long)bv * foN + c];
    for (int s = 0; s < SS; s++) {
        int col = s * outC + c;
        float s0 = sd[col], s1 = sd[SC + col], s2 = sd[2 * SC + col];
        float m = -1e30f;
#pragma unroll
        for (int n = 0; n < KNB; n++) {
            float dot = snd[n][0] * s0 + snd[n][1] * s1 + snd[n][2] * s2;
            float th = fmaxf(dot, 0.f);
            float sup = fo[(long)srow[n] * foN + outC + col];
            m = fmaxf(m, th * sup);
        }
        acc += m;
    }
    out[(long)bv * outC + c] = acc;
    if (fgmax) atomicMax(&fgmax[b * outC + c], fenc(acc));
}

// ---------------------------------------------------------------- batchnorm stats
__global__ __launch_bounds__(256) void bn_stat_kernel(const float* __restrict__ x,
                                                      float* __restrict__ stat, int R, int C) {
    int rp = 256 / C;
    int c = threadIdx.x % C;
    int rs = threadIdx.x / C;
    float s = 0.f, s2 = 0.f;
    for (long r = (long)blockIdx.x * rp + rs; r < R; r += (long)gridDim.x * rp) {
        float v = x[r * C + c];
        s += v; s2 += v * v;
    }
    atomicAdd(&stat[c], s);
    atomicAdd(&stat[C + c], s2);
}

__global__ void bn_apply_relu_kernel(const float* __restrict__ x, const float* __restrict__ stat,
                                     const float* __restrict__ g, const float* __restrict__ be,
                                     float* __restrict__ out, ushort* __restrict__ outb, int R, int C) {
    long i = blockIdx.x * 256L + threadIdx.x;
    if (i >= (long)R * C) return;
    int c = (int)(i % C);
    float mu = stat[c] / R;
    float var = stat[C + c] / R - mu * mu;
    var = fmaxf(var, 0.f);
    float y = (x[i] - mu) * rsqrtf(var + 1e-5f) * g[c] + be[c];
    y = fmaxf(y, 0.f);
    out[i] = y;
    if (outb) outb[i] = f2bf(y);
}

// ---------------------------------------------------------------- pool -> bf16
__global__ void pool_b_kernel(const float* __restrict__ fm, const int* __restrict__ idx,
                              ushort* __restrict__ out, int Vin, int T, int C) {
    long i = blockIdx.x * 256L + threadIdx.x;
    if (i >= (long)BSZ * T * C) return;
    int c = (int)(i % C);
    long bt = i / C;
    int b = (int)(bt / T), t = (int)(bt % T);
    const int* id = idx + ((long)b * T + t) * 4;
    float m = -1e30f;
#pragma unroll
    for (int n = 0; n < 4; n++)
        m = fmaxf(m, fm[((long)b * Vin + id[n]) * C + c]);
    out[i] = f2bf(m);
}

// ---------------------------------------------------------------- bf16 MFMA GEMM, 128x128 tile (async LDS)
__global__ __launch_bounds__(256) void gemm_mfma_bt_kernel(
    const ushort* __restrict__ A, const ushort* __restrict__ Bt,
    const float* __restrict__ bias, float* __restrict__ Cf, ushort* __restrict__ Cb,
    int M, int N, int K, int relu)
{
    __shared__ ushort As[128 * 32];
    __shared__ ushort Bs[128 * 32];
    int t = threadIdx.x;
    int w = t >> 6, l = t & 63;
    int quad = l >> 4, lm = l & 15;
    int wm = w >> 1, wn = w & 1;
    long m0 = blockIdx.y * 128L;
    long n0 = blockIdx.x * 128L;
    int lr = t >> 2;
    int lk = (t & 3) * 8;
    f32x4 acc[4][4];
#pragma unroll
    for (int i = 0; i < 4; i++)
#pragma unroll
        for (int j = 0; j < 4; j++) acc[i][j] = (f32x4){0.f, 0.f, 0.f, 0.f};

    for (int k0 = 0; k0 < K; k0 += 32) {
        __syncthreads();
        gl2lds16(A + (m0 + lr) * K + k0 + lk, &As[lr * 32 + lk]);
        gl2lds16(A + (m0 + 64 + lr) * K + k0 + lk, &As[(64 + lr) * 32 + lk]);
        gl2lds16(Bt + (n0 + lr) * K + k0 + lk, &Bs[lr * 32 + lk]);
        gl2lds16(Bt + (n0 + 64 + lr) * K + k0 + lk, &Bs[(64 + lr) * 32 + lk]);
        __syncthreads();
        short8 af[4], bfr[4];
#pragma unroll
        for (int i = 0; i < 4; i++)
            af[i] = *(const short8*)&As[(wm * 64 + i * 16 + lm) * 32 + quad * 8];
#pragma unroll
        for (int j = 0; j < 4; j++)
            bfr[j] = *(const short8*)&Bs[(wn * 64 + j * 16 + lm) * 32 + quad * 8];
#pragma unroll
        for (int i = 0; i < 4; i++)
#pragma unroll
            for (int j = 0; j < 4; j++)
                acc[i][j] = __builtin_amdgcn_mfma_f32_16x16x32_bf16(af[i], bfr[j], acc[i][j], 0, 0, 0);
    }
#pragma unroll
    for (int i = 0; i < 4; i++) {
#pragma unroll
        for (int j = 0; j < 4; j++) {
            int n = (int)n0 + wn * 64 + j * 16 + lm;
            float bv = bias[n];
#pragma unroll
            for (int r = 0; r < 4; r++) {
                int m = (int)m0 + wm * 64 + i * 16 + quad * 4 + r;
                float v = acc[i][j][r] + bv;
                if (relu) v = fmaxf(v, 0.f);
                if (Cf) Cf[(long)m * N + n] = v;
                if (Cb) Cb[(long)m * N + n] = f2bf(v);
            }
        }
    }
}

// ---------------------------------------------------------------- bf16 MFMA GEMM, 64x128 tile (async LDS)
__global__ __launch_bounds__(256) void gemm_mfma_bt64_kernel(
    const ushort* __restrict__ A, const ushort* __restrict__ Bt,
    const float* __restrict__ bias, float* __restrict__ Cf, ushort* __restrict__ Cb,
    int M, int N, int K, int relu)
{
    __shared__ ushort As[64 * 32];
    __shared__ ushort Bs[128 * 32];
    int t = threadIdx.x;
    int w = t >> 6, l = t & 63;
    int quad = l >> 4, lm = l & 15;
    int wm = w >> 1, wn = w & 1;
    long m0 = blockIdx.y * 64L;
    long n0 = blockIdx.x * 128L;
    int lr = t >> 2;
    int lk = (t & 3) * 8;
    f32x4 acc[2][4];
#pragma unroll
    for (int i = 0; i < 2; i++)
#pragma unroll
        for (int j = 0; j < 4; j++) acc[i][j] = (f32x4){0.f, 0.f, 0.f, 0.f};

    for (int k0 = 0; k0 < K; k0 += 32) {
        __syncthreads();
        gl2lds16(A + (m0 + lr) * K + k0 + lk, &As[lr * 32 + lk]);
        gl2lds16(Bt + (n0 + lr) * K + k0 + lk, &Bs[lr * 32 + lk]);
        gl2lds16(Bt + (n0 + 64 + lr) * K + k0 + lk, &Bs[(64 + lr) * 32 + lk]);
        __syncthreads();
        short8 af[2], bfr[4];
#pragma unroll
        for (int i = 0; i < 2; i++)
            af[i] = *(const short8*)&As[(wm * 32 + i * 16 + lm) * 32 + quad * 8];
#pragma unroll
        for (int j = 0; j < 4; j++)
            bfr[j] = *(const short8*)&Bs[(wn * 64 + j * 16 + lm) * 32 + quad * 8];
#pragma unroll
        for (int i = 0; i < 2; i++)
#pragma unroll
            for (int j = 0; j < 4; j++)
                acc[i][j] = __builtin_amdgcn_mfma_f32_16x16x32_bf16(af[i], bfr[j], acc[i][j], 0, 0, 0);
    }
#pragma unroll
    for (int i = 0; i < 2; i++) {
#pragma unroll
        for (int j = 0; j < 4; j++) {
            int n = (int)n0 + wn * 64 + j * 16 + lm;
            float bv = bias[n];
#pragma unroll
            for (int r = 0; r < 4; r++) {
                int m = (int)m0 + wm * 32 + i * 16 + quad * 4 + r;
                float v = acc[i][j][r] + bv;
                if (relu) v = fmaxf(v, 0.f);
                if (Cf) Cf[(long)m * N + n] = v;
                if (Cb) Cb[(long)m * N + n] = f2bf(v);
            }
        }
    }
}

// ---------------------------------------------------------------- bf16 MFMA GEMM, 64x64 tile (async LDS)
// For skinny-N / skinny-M shapes where 128-wide tiles starve the grid (wc1/wc2: N=512; layer4: M=512).
// Same staging/fragment/epilogue pattern as bt64; B-tile halved -> 2x the blocks.
__global__ __launch_bounds__(256) void gemm_mfma_bt6464_kernel(
    const ushort* __restrict__ A, const ushort* __restrict__ Bt,
    const float* __restrict__ bias, float* __restrict__ Cf, ushort* __restrict__ Cb,
    int M, int N, int K, int relu)
{
    __shared__ ushort As[64 * 32];
    __shared__ ushort Bs[64 * 32];
    int t = threadIdx.x;
    int w = t >> 6, l = t & 63;
    int quad = l >> 4, lm = l & 15;
    int wm = w >> 1, wn = w & 1;
    long m0 = blockIdx.y * 64L;
    long n0 = blockIdx.x * 64L;
    int lr = t >> 2;
    int lk = (t & 3) * 8;
    f32x4 acc[2][2];
#pragma unroll
    for (int i = 0; i < 2; i++)
#pragma unroll
        for (int j = 0; j < 2; j++) acc[i][j] = (f32x4){0.f, 0.f, 0.f, 0.f};

    for (int k0 = 0; k0 < K; k0 += 32) {
        __syncthreads();
        gl2lds16(A + (m0 + lr) * K + k0 + lk, &As[lr * 32 + lk]);
        gl2lds16(Bt + (n0 + lr) * K + k0 + lk, &Bs[lr * 32 + lk]);
        __syncthreads();
        short8 af[2], bfr[2];
#pragma unroll
        for (int i = 0; i < 2; i++)
            af[i] = *(const short8*)&As[(wm * 32 + i * 16 + lm) * 32 + quad * 8];
#pragma unroll
        for (int j = 0; j < 2; j++)
            bfr[j] = *(const short8*)&Bs[(wn * 32 + j * 16 + lm) * 32 + quad * 8];
#pragma unroll
        for (int i = 0; i < 2; i++)
#pragma unroll
            for (int j = 0; j < 2; j++)
                acc[i][j] = __builtin_amdgcn_mfma_f32_16x16x32_bf16(af[i], bfr[j], acc[i][j], 0, 0, 0);
    }
#pragma unroll
    for (int i = 0; i < 2; i++) {
#pragma unroll
        for (int j = 0; j < 2; j++) {
            int n = (int)n0 + wn * 32 + j * 16 + lm;
            float bv = bias[n];
#pragma unroll
            for (int r = 0; r < 4; r++) {
                int m = (int)m0 + wm * 32 + i * 16 + quad * 4 + r;
                float v = acc[i][j][r] + bv;
                if (relu) v = fmaxf(v, 0.f);
                if (Cf) Cf[(long)m * N + n] = v;
                if (Cb) Cb[(long)m * N + n] = f2bf(v);
            }
        }
    }
}

// ---------------------------------------------------------------- wc3 head
__global__ __launch_bounds__(256) void wc3_kernel(const float* __restrict__ h2,
                                                  const float* __restrict__ wc3t,
                                                  const float* __restrict__ bc3,
                                                  float* __restrict__ out) {
    int r8 = threadIdx.x >> 5;
    int c = threadIdx.x & 31;
    long row = blockIdx.x * 8L + r8;
    const float* hr = h2 + row * 512;
    float acc = 0.f;
    if (c < 30) {
        for (int k = 0; k < 512; k++)
            acc += hr[k] * wc3t[k * 30 + c];
        acc += bc3[c];
        if (c < 6) out[row * 6 + c] = acc;
        else       out[49152 + row * 24 + (c - 6)] = acc;
    }
}

// ---------------------------------------------------------------- fuse (row-per-block)
__global__ __launch_bounds__(256) void fuse_bf_kernel(
    const float* __restrict__ fm0, const float* __restrict__ fm1,
    const float* __restrict__ fm2, const float* __restrict__ fm3,
    const float* __restrict__ fm4, const unsigned* __restrict__ fg_enc,
    const float* __restrict__ onehot,
    const int* __restrict__ n1, const int* __restrict__ n2,
    ushort* __restrict__ fuse_b, float* __restrict__ feat) {
    long row = blockIdx.x;
    int b = (int)(row >> 11);
    int i1 = n1[row], i2 = n2[row];
    const float* p0 = fm0 + row * 128;
    const float* p1 = fm1 + row * 128;
    const float* p2 = fm2 + ((long)b * 512 + i1) * 256;
    const float* p3 = fm3 + ((long)b * 512 + i1) * 256;
    const float* p4 = fm4 + ((long)b * 128 + i2) * 512;
    const unsigned* pg = fg_enc + b * 512;
    const float* po = onehot + b * 16;
    ushort* fb = fuse_b + row * 1824;
    float* ft = feat + row * 1296;
#pragma unroll
    for (int k = 0; k < 8; k++) {
        int c = threadIdx.x + k * 256;
        if (c >= 1824) break;
        float val = 0.f;
        if (c < 128)       val = p0[c];
        else if (c < 256)  val = p1[c - 128];
        else if (c < 512)  val = p2[c - 256];
        else if (c < 768)  val = p3[c - 512];
        else if (c < 1280) val = p4[c - 768];
        else if (c < 1792) val = fdec(pg[c - 1280]);
        else if (c < 1808) val = po[c - 1792];
        fb[c] = f2bf(val);
        if (c < 1280)                   ft[c] = val;
        else if (c >= 1792 && c < 1808) ft[c - 512] = val;
    }
}

// ---------------------------------------------------------------- launch

extern "C" void kernel_launch(void* const* d_in, const int* in_sizes, int n_in,
                              void* d_out, int out_size, void* d_ws, size_t ws_size,
                              hipStream_t stream) {
    const float* verts  = (const float*)d_in[0];
    const float* onehot = (const float*)d_in[1];
    const float* dir0 = (const float*)d_in[2];
    const float* w1 = (const float*)d_in[3];
    const float* b1 = (const float*)d_in[4];
    const float* dir1 = (const float*)d_in[5];
    const float* w2 = (const float*)d_in[6];
    const float* b2 = (const float*)d_in[7];
    const float* dir2 = (const float*)d_in[8];
    const float* w3 = (const float*)d_in[9];
    const float* b3 = (const float*)d_in[10];
    const float* dir3 = (const float*)d_in[11];
    const float* w4 = (const float*)d_in[12];
    const float* b4 = (const float*)d_in[13];
    const float* dir4 = (const float*)d_in[14];
    const float* g_bn1 = (const float*)d_in[15];
    const float* be_bn1 = (const float*)d_in[16];
    const float* g_bn2 = (const float*)d_in[17];
    const float* be_bn2 = (const float*)d_in[18];
    const float* g_bn3 = (const float*)d_in[19];
    const float* be_bn3 = (const float*)d_in[20];
    const float* wc1 = (const float*)d_in[21];
    const float* bc1 = (const float*)d_in[22];
    const float* wc2 = (const float*)d_in[23];
    const float* bc2 = (const float*)d_in[24];
    const float* wc3 = (const float*)d_in[25];
    const float* bc3 = (const float*)d_in[26];
    float* outf = (float*)d_out;

    float* wsf = (float*)d_ws;
    size_t off = 0;
    auto alloc = [&](size_t n) { float* p = wsf + off; off += (n + 15) & ~(size_t)15; return p; };

    float* sd0 = alloc(3 * 896);
    float* sd1 = alloc(3 * 896);
    float* sd2 = alloc(3 * 1792);
    float* sd3 = alloc(3 * 1792);
    float* sd4 = alloc(3 * 3584);
    float* wc3t = alloc(512L * 30);
    float* fm0 = alloc(8192L * 128);
    float* fm1 = alloc(8192L * 128);
    float* c1  = alloc(8192L * 128);
    float* fm2 = alloc(2048L * 256);
    float* c2  = alloc(2048L * 256);
    float* fm3 = alloc(2048L * 256);
    float* c3  = alloc(2048L * 256);
    float* fm4 = alloc(512L * 512);
    float* statbase = alloc(3328);
    float* stat1 = statbase;
    float* stat2 = statbase + 256;
    float* stat3 = statbase + 768;
    unsigned* fg_enc = (unsigned*)(statbase + 1280);
    float* fbuf = alloc(8192L * 1024);
    float* h2 = alloc(8192L * 512);
    float* pd  = alloc(KTOT);
    ushort* pi = (ushort*)alloc(KTOT / 2);
    int* nb   = (int*)alloc(8192L * KNB);
    int* nb1  = (int*)alloc(2048L * KNB);
    int* nb2  = (int*)alloc(512L * KNB);
    int* nbp1 = (int*)alloc(2048L * 4);
    int* nbp2 = (int*)alloc(512L * 4);
    int* n1   = (int*)alloc(8192);
    int* n2   = (int*)alloc(8192);
    ushort* fuse_b = (ushort*)alloc(8192L * 1824 / 2);
    ushort* h1b    = (ushort*)alloc(8192L * 512 / 2);
    ushort* wc1b   = (ushort*)alloc(512L * 1824 / 2);
    ushort* wc2b   = (ushort*)alloc(512L * 512 / 2);
    ushort* w1tb   = (ushort*)alloc(1024L * 128 / 2);
    ushort* w2tb   = (ushort*)alloc(2048L * 128 / 2);
    ushort* w3tb   = (ushort*)alloc(2048L * 256 / 2);
    ushort* w4tb   = (ushort*)alloc(4096L * 256 / 2);
    ushort* fm0b   = (ushort*)alloc(8192L * 128 / 2);
    ushort* fp1b   = (ushort*)alloc(2048L * 128 / 2);
    ushort* fm2b   = (ushort*)alloc(2048L * 256 / 2);
    ushort* fp2b   = (ushort*)alloc(512L * 256 / 2);

    auto nblk = [](long n, int b) { return (unsigned)((n + b - 1) / b); };

    hipMemsetAsync(statbase, 0, 3328 * sizeof(float), stream);

    // fused front: knn partials + nearest + prep + weight transpose (mutually independent)
    front_uber<<<1088 + PREP_BLOCKS + 1920, 256, 0, stream>>>(
        verts, pd, pi, n1, n2,
        dir0, dir1, dir2, dir3, dir4, sd0, sd1, sd2, sd3, sd4,
        wc3, wc3t, wc1, wc1b, wc2, wc2b,
        w1, w2, w3, w4, w1tb, w2tb, w3tb, w4tb);

    knn_merge_uber<<<2184, 256, 0, stream>>>(pd, pi, nb, nb1, nb2, nbp1, nbp2);

    conv_surface_kernel<<<BSZ * 2048, 128, 0, stream>>>(verts, nb, sd0, fm0, fm0b);

    // layer1 (M=8192, N=1024, K=128)
    gemm_mfma_bt_kernel<<<dim3(8, 64), 256, 0, stream>>>(fm0b, w1tb, b1, fbuf, nullptr, 8192, 1024, 128, 0);
    conv_act_kernel<<<BSZ * 2048, 128, 0, stream>>>(verts, nb, sd1, fbuf, c1, nullptr, 2048, 128);
    bn_stat_kernel<<<256, 256, 0, stream>>>(c1, stat1, 8192, 128);
    bn_apply_relu_kernel<<<nblk(8192L * 128, 256), 256, 0, stream>>>(c1, stat1, g_bn1, be_bn1, fm1, nullptr, 8192, 128);

    pool_b_kernel<<<nblk(BSZ * 512L * 128, 256), 256, 0, stream>>>(fm1, nbp1, fp1b, 2048, 512, 128);

    // layer2 (M=2048, N=2048, K=128)
    gemm_mfma_bt64_kernel<<<dim3(16, 32), 256, 0, stream>>>(fp1b, w2tb, b2, fbuf, nullptr, 2048, 2048, 128, 0);
    conv_act_kernel<<<BSZ * 512, 256, 0, stream>>>(verts, nb1, sd2, fbuf, c2, nullptr, 512, 256);
    bn_stat_kernel<<<256, 256, 0, stream>>>(c2, stat2, 2048, 256);
    bn_apply_relu_kernel<<<nblk(2048L * 256, 256), 256, 0, stream>>>(c2, stat2, g_bn2, be_bn2, fm2, fm2b, 2048, 256);

    // layer3 (M=2048, N=2048, K=256)
    gemm_mfma_bt64_kernel<<<dim3(16, 32), 256, 0, stream>>>(fm2b, w3tb, b3, fbuf, nullptr, 2048, 2048, 256, 0);
    conv_act_kernel<<<BSZ * 512, 256, 0, stream>>>(verts, nb1, sd3, fbuf, c3, nullptr, 512, 256);
    bn_stat_kernel<<<256, 256, 0, stream>>>(c3, stat3, 2048, 256);
    bn_apply_relu_kernel<<<nblk(2048L * 256, 256), 256, 0, stream>>>(c3, stat3, g_bn3, be_bn3, fm3, nullptr, 2048, 256);

    pool_b_kernel<<<nblk(BSZ * 128L * 256, 256), 256, 0, stream>>>(fm3, nbp2, fp2b, 512, 128, 256);

    // layer4 (M=512, N=4096, K=256) -- 64x64 tile: 512 blocks (2/CU) vs 256 (1/CU)
    gemm_mfma_bt6464_kernel<<<dim3(64, 8), 256, 0, stream>>>(fp2b, w4tb, b4, fbuf, nullptr, 512, 4096, 256, 0);
    conv_act_kernel<<<BSZ * 128, 512, 0, stream>>>(verts, nb2, sd4, fbuf, fm4, fg_enc, 128, 512);

    // fuse -> bf16 GEMM input + fp32 feat (direct to d_out)
    fuse_bf_kernel<<<8192, 256, 0, stream>>>(fm0, fm1, fm2, fm3, fm4, fg_enc, onehot,
                                             n1, n2, fuse_b, outf + 245760);

    // MLP head (M=8192, N=512) -- 64x64 tile: 1024 blocks (4/CU) vs 512 (2/CU)
    gemm_mfma_bt6464_kernel<<<dim3(8, 128), 256, 0, stream>>>(fuse_b, wc1b, bc1, nullptr, h1b, 8192, 512, 1824, 1);
    gemm_mfma_bt6464_kernel<<<dim3(8, 128), 256, 0, stream>>>(h1b, wc2b, bc2, h2, nullptr, 8192, 512, 512, 1);
    wc3_kernel<<<1024, 256, 0, stream>>>(h2, wc3t, bc3, outf);
}

// Round 11
// 455.764 us; speedup vs baseline: 1.0102x; 1.0102x over previous
//
#include <hip/hip_runtime.h>
#include <hip/hip_bf16.h>
#include <math.h>

#define BSZ 4
#define VN 2048
#define SS 7
#define KNB 10

typedef __attribute__((ext_vector_type(8))) short short8;
typedef __attribute__((ext_vector_type(4))) float f32x4;
typedef __attribute__((address_space(1))) const void gcvoid;
typedef __attribute__((address_space(3))) void lvoid;

__device__ inline ushort f2bf(float x) {
    __hip_bfloat16 h = __float2bfloat16(x);
    return *(ushort*)&h;
}

__device__ inline void gl2lds16(const ushort* g, ushort* l) {
    __builtin_amdgcn_global_load_lds((gcvoid*)g, (lvoid*)l, 16, 0, 0);
}

__device__ inline unsigned fenc(float f) {
    unsigned b = __float_as_uint(f);
    return (b & 0x80000000u) ? ~b : (b | 0x80000000u);
}
__device__ inline float fdec(unsigned e) {
    unsigned b = (e & 0x80000000u) ? (e & 0x7FFFFFFFu) : ~e;
    return __uint_as_float(b);
}

#define INS(dq, iq, dd, jj) { bool lt_ = (dd) < (dq); \
    float dmn_ = lt_ ? (dd) : (dq); float dmx_ = lt_ ? (dq) : (dd); \
    int imn_ = lt_ ? (jj) : (iq); int imx_ = lt_ ? (iq) : (jj); \
    (dq) = dmn_; (iq) = imn_; (dd) = dmx_; (jj) = imx_; }

// ---------------------------------------------------------------- prep (device fn; part of front_uber)
#define PB0 8960L
#define PB1 24320L
#define PB2 958208L
#define PB3 1220352L
#define PREP_BLOCKS 4767        // PB3 / 256

__device__ void prep_dev(int gb,
                         const float* __restrict__ d0, const float* __restrict__ d1,
                         const float* __restrict__ d2, const float* __restrict__ d3,
                         const float* __restrict__ d4,
                         float* __restrict__ s0, float* __restrict__ s1,
                         float* __restrict__ s2, float* __restrict__ s3, float* __restrict__ s4,
                         const float* __restrict__ wc3, float* __restrict__ wc3t,
                         const float* __restrict__ wc1, ushort* __restrict__ wc1b,
                         const float* __restrict__ wc2, ushort* __restrict__ wc2b) {
    long i = gb * 256L + threadIdx.x;
    if (i < PB0) {
        const float* src; float* dst; int C, c;
        if (i < 896)        { src = d0; dst = s0; C = 896;  c = (int)i; }
        else if (i < 1792)  { src = d1; dst = s1; C = 896;  c = (int)i - 896; }
        else if (i < 3584)  { src = d2; dst = s2; C = 1792; c = (int)i - 1792; }
        else if (i < 5376)  { src = d3; dst = s3; C = 1792; c = (int)i - 3584; }
        else                { src = d4; dst = s4; C = 3584; c = (int)i - 5376; }
        float a = src[c], b = src[C + c], e = src[2 * C + c];
        float den = fmaxf(sqrtf(a * a + b * b + e * e), 1e-12f);
        dst[c] = a / den; dst[C + c] = b / den; dst[2 * C + c] = e / den;
    } else if (i < PB1) {
        long j = i - PB0;
        int o = (int)(j / 512), k = (int)(j % 512);
        wc3t[(long)k * 30 + o] = wc3[j];
    } else if (i < PB2) {
        long j = i - PB1;
        int c = (int)(j % 1824);
        long r = j / 1824;
        wc1b[j] = f2bf(c < 1808 ? wc1[r * 1808 + c] : 0.f);
    } else if (i < PB3) {
        long j = i - PB2;
        wc2b[j] = f2bf(wc2[j]);
    }
}

// ---------------------------------------------------------------- weight transpose (device fn; part of front_uber)
__device__ void wt_trans_dev(int gb, float* tilef,
                             const float* __restrict__ w1, const float* __restrict__ w2,
                             const float* __restrict__ w3, const float* __restrict__ w4,
                             ushort* __restrict__ o1, ushort* __restrict__ o2,
                             ushort* __restrict__ o3, ushort* __restrict__ o4) {
    const float* w; ushort* o; int K, N, t;
    if (gb < 128)      { w = w1; o = o1; K = 128; N = 1024; t = gb; }
    else if (gb < 384) { w = w2; o = o2; K = 128; N = 2048; t = gb - 128; }
    else if (gb < 896) { w = w3; o = o3; K = 256; N = 2048; t = gb - 384; }
    else               { w = w4; o = o4; K = 256; N = 4096; t = gb - 896; }
    int tn = t % (N / 32), tk = t / (N / 32);
    int n0 = tn * 32, k0 = tk * 32;
    int tx = threadIdx.x % 32, ty = threadIdx.x / 32;
#pragma unroll
    for (int r = 0; r < 32; r += 8)
        tilef[(ty + r) * 33 + tx] = w[(long)(k0 + ty + r) * N + n0 + tx];
    __syncthreads();
#pragma unroll
    for (int r = 0; r < 32; r += 8)
        o[(long)(n0 + ty + r) * K + k0 + tx] = f2bf(tilef[tx * 33 + ty + r]);
}

// ---------------------------------------------------------------- knn part (exact fp32, 64-source chunks)
// Only the 2048x2048 pass is computed: pooled point sets vp1/vp2 are PREFIXES of vertices
// (verts[:, :512], verts[:, :128]), so their partial lists are sub-slices of the big run.
// per target, per 64-source chunk: 2 sorted 10-lists (sublists of 32 sources, ascending index ranges)
// pd[ ((b*2048 + i)*32 + ch)*20 + l*10 + q ] == row (b*2048+i), list c=2*ch+l at (row*64+c)*10
#define KTOT  5242880L

__device__ void knn_part_dev(const float* __restrict__ verts, int T, int nch,
                             int tile, int b, int ch,
                             float* __restrict__ pd, ushort* __restrict__ pi,
                             float4* __restrict__ s4) {
    const float* vb = verts + (long)b * VN * 3;
    int j0 = ch * 64;
    for (int j = threadIdx.x; j < 64; j += 256) {
        float x = vb[(j0 + j) * 3 + 0];
        float y = vb[(j0 + j) * 3 + 1];
        float z = vb[(j0 + j) * 3 + 2];
        s4[j] = make_float4(x, y, z, x * x + y * y + z * z);
    }
    __syncthreads();
    int i = tile * 256 + (int)threadIdx.x;
    if (i >= T) return;
    float px = vb[i * 3], py = vb[i * 3 + 1], pz = vb[i * 3 + 2];
    float d0[10], d1[10];
    int id0[10], id1[10];
#pragma unroll
    for (int q = 0; q < 10; q++) {
        d0[q] = 1e30f; d1[q] = 1e30f;
        id0[q] = 0; id1[q] = 0;
    }
    for (int j = 0; j < 32; j++) {
        float4 sA = s4[j];
        float4 sB = s4[32 + j];
        float dA = fmaf(-2.f, px * sA.x + py * sA.y + pz * sA.z, sA.w);
        float dB = fmaf(-2.f, px * sB.x + py * sB.y + pz * sB.z, sB.w);
        int jA = j0 + j, jB = j0 + 32 + j;
        dA = (jA == i) ? 1e30f : dA;
        dB = (jB == i) ? 1e30f : dB;
#pragma unroll
        for (int q = 0; q < 10; q++) { INS(d0[q], id0[q], dA, jA); }
#pragma unroll
        for (int q = 0; q < 10; q++) { INS(d1[q], id1[q], dB, jB); }
    }
    long base = ((long)(b * T + i) * nch + ch) * 20;
    // vectorized stores: base is a multiple of 20 floats (80B) -> list0 16B-aligned, list1 (+40B) 8B-aligned
    *(float4*)(pd + base)      = make_float4(d0[0], d0[1], d0[2], d0[3]);
    *(float4*)(pd + base + 4)  = make_float4(d0[4], d0[5], d0[6], d0[7]);
    *(float2*)(pd + base + 8)  = make_float2(d0[8], d0[9]);
    *(float2*)(pd + base + 10) = make_float2(d1[0], d1[1]);
    *(float2*)(pd + base + 12) = make_float2(d1[2], d1[3]);
    *(float2*)(pd + base + 14) = make_float2(d1[4], d1[5]);
    *(float2*)(pd + base + 16) = make_float2(d1[6], d1[7]);
    *(float2*)(pd + base + 18) = make_float2(d1[8], d1[9]);
    // index pairs packed little-endian u16|u16<<16 == the u32 words the merge reads
    uint* pu = (uint*)(pi + base);
#pragma unroll
    for (int q = 0; q < 5; q++)
        pu[q] = (uint)(ushort)id0[2 * q] | ((uint)(ushort)id0[2 * q + 1] << 16);
#pragma unroll
    for (int q = 0; q < 5; q++)
        pu[5 + q] = (uint)(ushort)id1[2 * q] | ((uint)(ushort)id1[2 * q + 1] << 16);
}

__device__ void nearest_dev(const float* __restrict__ verts, int SN, int* __restrict__ out,
                            int gl, float4* __restrict__ s4) {
    int t = gl * 256 + (int)threadIdx.x;
    int b = t / VN;
    const float* vb = verts + (long)b * VN * 3;
    for (int j = threadIdx.x; j < SN; j += 256) {
        float x = vb[j * 3], y = vb[j * 3 + 1], z = vb[j * 3 + 2];
        s4[j] = make_float4(x, y, z, x * x + y * y + z * z);
    }
    __syncthreads();
    int i = t % VN;
    float px = vb[i * 3], py = vb[i * 3 + 1], pz = vb[i * 3 + 2];
    int h = SN / 2;
    float b0 = 1e30f, b1 = 1e30f; int i0 = 0, i1 = 0;
    for (int j = 0; j < h; j++) {
        float4 sA = s4[j];
        float4 sB = s4[h + j];
        float dA = fmaf(-2.f, px * sA.x + py * sA.y + pz * sA.z, sA.w);
        float dB = fmaf(-2.f, px * sB.x + py * sB.y + pz * sB.z, sB.w);
        bool lA = dA < b0; b0 = lA ? dA : b0; i0 = lA ? j : i0;
        bool lB = dB < b1; b1 = lB ? dB : b1; i1 = lB ? (h + j) : i1;
    }
    out[t] = (b1 < b0) ? i1 : i0;
}

// ---------------------------------------------------------------- front uber: knn part + nearest + prep + weight transpose
//  [0,1024)        knn big: 8 tiles x (4 b x 32 ch)   2048x2048
//  [1024,1056)     nearest n1 (512 sources)
//  [1056,1088)     nearest n2 (128 sources)
//  [1088,5855)     prep (4767 blocks)
//  [5855,7775)     weight transpose (1920 blocks)
__global__ __launch_bounds__(256) void front_uber(const float* __restrict__ verts,
                                                  float* __restrict__ pd, ushort* __restrict__ pi,
                                                  int* __restrict__ n1, int* __restrict__ n2,
                                                  const float* __restrict__ d0, const float* __restrict__ d1,
                                                  const float* __restrict__ d2, const float* __restrict__ d3,
                                                  const float* __restrict__ d4,
                                                  float* __restrict__ s0, float* __restrict__ s1,
                                                  float* __restrict__ s2, float* __restrict__ s3,
                                                  float* __restrict__ s4v,
                                                  const float* __restrict__ wc3, float* __restrict__ wc3t,
                                                  const float* __restrict__ wc1, ushort* __restrict__ wc1b,
                                                  const float* __restrict__ wc2, ushort* __restrict__ wc2b,
                                                  const float* __restrict__ w1, const float* __restrict__ w2,
                                                  const float* __restrict__ w3, const float* __restrict__ w4,
                                                  ushort* __restrict__ o1, ushort* __restrict__ o2,
                                                  ushort* __restrict__ o3, ushort* __restrict__ o4) {
    __shared__ float4 smem[512];        // knn/nearest: float4[512]; trans: float[32][33] alias
    int gb = blockIdx.x;
    if (gb < 1024) {
        int tile = gb & 7, bc = gb >> 3;
        knn_part_dev(verts, 2048, 32, tile, bc >> 5, bc & 31, pd, pi, smem);
    } else if (gb < 1056) {
        nearest_dev(verts, 512, n1, gb - 1024, smem);
    } else if (gb < 1088) {
        nearest_dev(verts, 128, n2, gb - 1056, smem);
    } else if (gb < 1088 + PREP_BLOCKS) {
        prep_dev(gb - 1088, d0, d1, d2, d3, d4, s0, s1, s2, s3, s4v,
                 wc3, wc3t, wc1, wc1b, wc2, wc2b);
    } else {
        wt_trans_dev(gb - (1088 + PREP_BLOCKS), (float*)smem, w1, w2, w3, w4, o1, o2, o3, o4);
    }
}

// ---------------------------------------------------------------- knn selection: lane-per-list tournament
template <int G>
__device__ void knn_sel_dev(const float* __restrict__ pd, const ushort* __restrict__ pi,
                            int blk, int Tsub, int* __restrict__ out,
                            int* __restrict__ outp, int Tp) {
    typedef unsigned long long u64;
    constexpr int TPB = 256 / G;        // targets per block
    int tid = threadIdx.x;
    long t = (long)blk * TPB + (tid / G);
    int c = tid % G;
    int bb = (int)(t / Tsub), ii = (int)(t % Tsub);
    long row = (long)bb * 2048 + ii;
    long base = (row * 64 + c) * 10;
    const float2* pf = (const float2*)(pd + base);   // 40B stride -> 8B aligned
    const uint*   pu = (const uint*)(pi + base);     // 20B stride -> 4B aligned
    float2 f0 = pf[0], f1 = pf[1], f2 = pf[2], f3 = pf[3], f4 = pf[4];
    uint   u0 = pu[0], u1 = pu[1], u2 = pu[2], u3 = pu[3], u4 = pu[4];
    u64 k0 = ((u64)fenc(f0.x) << 32) | (u0 & 0xFFFFu);
    u64 k1 = ((u64)fenc(f0.y) << 32) | (u0 >> 16);
    u64 k2 = ((u64)fenc(f1.x) << 32) | (u1 & 0xFFFFu);
    u64 k3 = ((u64)fenc(f1.y) << 32) | (u1 >> 16);
    u64 k4 = ((u64)fenc(f2.x) << 32) | (u2 & 0xFFFFu);
    u64 k5 = ((u64)fenc(f2.y) << 32) | (u2 >> 16);
    u64 k6 = ((u64)fenc(f3.x) << 32) | (u3 & 0xFFFFu);
    u64 k7 = ((u64)fenc(f3.y) << 32) | (u3 >> 16);
    u64 k8 = ((u64)fenc(f4.x) << 32) | (u4 & 0xFFFFu);
    u64 k9 = ((u64)fenc(f4.y) << 32) | (u4 >> 16);
    bool wp = (outp != nullptr) && (ii < Tp);
#pragma unroll
    for (int q = 0; q < 10; q++) {
        u64 m = k0;
#pragma unroll
        for (int s = 1; s < G; s <<= 1) {
            u64 o = (u64)__shfl_xor((long long)m, s);
            m = (o < m) ? o : m;
        }
        if (c == 0) {
            int idx = (int)(unsigned)(m & 0xFFFFFFFFull);
            out[t * 10 + q] = idx;
            if (wp && q < 4) outp[((long)bb * Tp + ii) * 4 + q] = idx;
        }
        if (k0 == m) {
            k0 = k1; k1 = k2; k2 = k3; k3 = k4; k4 = k5;
            k5 = k6; k6 = k7; k7 = k8; k8 = k9;
            k9 = 0xFFFFFFFFFFFFFFFFull;
        }
    }
}

// grid: [0,2048) big (8192 t, 64 lists, 4 t/blk) | [2048,2176) mid (2048 t, 16 lists, 16 t/blk)
//       | [2176,2184) small (512 t, 4 lists, 64 t/blk)
__global__ __launch_bounds__(256) void knn_merge_uber(const float* __restrict__ pd, const ushort* __restrict__ pi,
                                                      int* __restrict__ nb, int* __restrict__ nb1,
                                                      int* __restrict__ nb2, int* __restrict__ nbp1,
                                                      int* __restrict__ nbp2) {
    int gb = blockIdx.x;
    if (gb < 2048)      knn_sel_dev<64>(pd, pi, gb, 2048, nb, nbp1, 512);
    else if (gb < 2176) knn_sel_dev<16>(pd, pi, gb - 2048, 512, nb1, nbp2, 128);
    else                knn_sel_dev<4>(pd, pi, gb - 2176, 128, nb2, nullptr, 1);
}

// ---------------------------------------------------------------- conv_surface (fp32 + bf16 out)
__global__ void conv_surface_kernel(const float* __restrict__ verts, const int* __restrict__ nb,
                                    const float* __restrict__ sd, float* __restrict__ fm0,
                                    ushort* __restrict__ fm0b) {
    int bv = blockIdx.x;
    int b = bv / VN, v = bv % VN;
    __shared__ float snd[KNB][3];
    int tid = threadIdx.x;
    if (tid < KNB) {
        int nj = nb[(long)bv * KNB + tid];
        const float* vb = verts + (long)b * VN * 3;
        float dx = vb[nj * 3] - vb[v * 3];
        float dy = vb[nj * 3 + 1] - vb[v * 3 + 1];
        float dz = vb[nj * 3 + 2] - vb[v * 3 + 2];
        float den = fmaxf(sqrtf(dx * dx + dy * dy + dz * dz), 1e-12f);
        snd[tid][0] = dx / den; snd[tid][1] = dy / den; snd[tid][2] = dz / den;
    }
    __syncthreads();
    int c = tid;
    float acc = 0.f;
    for (int s = 0; s < SS; s++) {
        int col = s * 128 + c;
        float s0 = sd[col], s1 = sd[896 + col], s2 = sd[2 * 896 + col];
        float m = 0.f;
#pragma unroll
        for (int n = 0; n < KNB; n++) {
            float dot = snd[n][0] * s0 + snd[n][1] * s1 + snd[n][2] * s2;
            m = fmaxf(m, dot);
        }
        acc += m;
    }
    fm0[(long)bv * 128 + c] = acc;
    fm0b[(long)bv * 128 + c] = f2bf(acc);
}

// ---------------------------------------------------------------- conv_layer act (+opt fg max)
__global__ void conv_act_kernel(const float* __restrict__ verts, const int* __restrict__ nb,
                                const float* __restrict__ sd, const float* __restrict__ fo,
                                float* __restrict__ out, unsigned* __restrict__ fgmax,
                                int Vl, int outC) {
    int bv = blockIdx.x;
    int b = bv / Vl, v = bv % Vl;
    __shared__ float snd[KNB][3];
    __shared__ int srow[KNB];
    int tid = threadIdx.x;
    if (tid < KNB) {
        int nj = nb[(long)bv * KNB + tid];
        srow[tid] = b * Vl + nj;
        const float* vb = verts + (long)b * VN * 3;
        float dx = vb[nj * 3] - vb[v * 3];
        float dy = vb[nj * 3 + 1] - vb[v * 3 + 1];
        float dz = vb[nj * 3 + 2] - vb[v * 3 + 2];
        float den = fmaxf(sqrtf(dx * dx + dy * dy + dz * dz), 1e-12f);
        snd[tid][0] = dx / den; snd[tid][1] = dy / den; snd[tid][2] = dz / den;
    }
    __syncthreads();
    int c = tid;
    int SC = SS * outC;
    int foN = SC + outC;
    float acc = fo[(long)bv * foN + c];
    for (int s = 0; s < SS; s++) {
        int col = s * outC + c;
        float s0 = sd[col], s1 = sd[SC + col], s2 = sd[2 * SC + col];
        float m = -1e30f;
#pragma unroll
        for (int n = 0; n < KNB; n++) {
            float dot = snd[n][0] * s0 + snd[n][1] * s1 + snd[n][2] * s2;
            float th = fmaxf(dot, 0.f);
            float sup = fo[(long)srow[n] * foN + outC + col];
            m = fmaxf(m, th * sup);
        }
        acc += m;
    }
    out[(long)bv * outC + c] = acc;
    if (fgmax) atomicMax(&fgmax[b * outC + c], fenc(acc));
}

// ---------------------------------------------------------------- batchnorm stats
__global__ __launch_bounds__(256) void bn_stat_kernel(const float* __restrict__ x,
                                                      float* __restrict__ stat, int R, int C) {
    int rp = 256 / C;
    int c = threadIdx.x % C;
    int rs = threadIdx.x / C;
    float s = 0.f, s2 = 0.f;
    for (long r = (long)blockIdx.x * rp + rs; r < R; r += (long)gridDim.x * rp) {
        float v = x[r * C + c];
        s += v; s2 += v * v;
    }
    atomicAdd(&stat[c], s);
    atomicAdd(&stat[C + c], s2);
}

__global__ void bn_apply_relu_kernel(const float* __restrict__ x, const float* __restrict__ stat,
                                     const float* __restrict__ g, const float* __restrict__ be,
                                     float* __restrict__ out, ushort* __restrict__ outb, int R, int C) {
    long i = blockIdx.x * 256L + threadIdx.x;
    if (i >= (long)R * C) return;
    int c = (int)(i % C);
    float mu = stat[c] / R;
    float var = stat[C + c] / R - mu * mu;
    var = fmaxf(var, 0.f);
    float y = (x[i] - mu) * rsqrtf(var + 1e-5f) * g[c] + be[c];
    y = fmaxf(y, 0.f);
    out[i] = y;
    if (outb) outb[i] = f2bf(y);
}

// ---------------------------------------------------------------- pool -> bf16
__global__ void pool_b_kernel(const float* __restrict__ fm, const int* __restrict__ idx,
                              ushort* __restrict__ out, int Vin, int T, int C) {
    long i = blockIdx.x * 256L + threadIdx.x;
    if (i >= (long)BSZ * T * C) return;
    int c = (int)(i % C);
    long bt = i / C;
    int b = (int)(bt / T), t = (int)(bt % T);
    const int* id = idx + ((long)b * T + t) * 4;
    float m = -1e30f;
#pragma unroll
    for (int n = 0; n < 4; n++)
        m = fmaxf(m, fm[((long)b * Vin + id[n]) * C + c]);
    out[i] = f2bf(m);
}

// ---------------------------------------------------------------- bf16 MFMA GEMM, 128x128 tile (async LDS)
__global__ __launch_bounds__(256) void gemm_mfma_bt_kernel(
    const ushort* __restrict__ A, const ushort* __restrict__ Bt,
    const float* __restrict__ bias, float* __restrict__ Cf, ushort* __restrict__ Cb,
    int M, int N, int K, int relu)
{
    __shared__ ushort As[128 * 32];
    __shared__ ushort Bs[128 * 32];
    int t = threadIdx.x;
    int w = t >> 6, l = t & 63;
    int quad = l >> 4, lm = l & 15;
    int wm = w >> 1, wn = w & 1;
    long m0 = blockIdx.y * 128L;
    long n0 = blockIdx.x * 128L;
    int lr = t >> 2;
    int lk = (t & 3) * 8;
    f32x4 acc[4][4];
#pragma unroll
    for (int i = 0; i < 4; i++)
#pragma unroll
        for (int j = 0; j < 4; j++) acc[i][j] = (f32x4){0.f, 0.f, 0.f, 0.f};

    for (int k0 = 0; k0 < K; k0 += 32) {
        __syncthreads();
        gl2lds16(A + (m0 + lr) * K + k0 + lk, &As[lr * 32 + lk]);
        gl2lds16(A + (m0 + 64 + lr) * K + k0 + lk, &As[(64 + lr) * 32 + lk]);
        gl2lds16(Bt + (n0 + lr) * K + k0 + lk, &Bs[lr * 32 + lk]);
        gl2lds16(Bt + (n0 + 64 + lr) * K + k0 + lk, &Bs[(64 + lr) * 32 + lk]);
        __syncthreads();
        short8 af[4], bfr[4];
#pragma unroll
        for (int i = 0; i < 4; i++)
            af[i] = *(const short8*)&As[(wm * 64 + i * 16 + lm) * 32 + quad * 8];
#pragma unroll
        for (int j = 0; j < 4; j++)
            bfr[j] = *(const short8*)&Bs[(wn * 64 + j * 16 + lm) * 32 + quad * 8];
#pragma unroll
        for (int i = 0; i < 4; i++)
#pragma unroll
            for (int j = 0; j < 4; j++)
                acc[i][j] = __builtin_amdgcn_mfma_f32_16x16x32_bf16(af[i], bfr[j], acc[i][j], 0, 0, 0);
    }
#pragma unroll
    for (int i = 0; i < 4; i++) {
#pragma unroll
        for (int j = 0; j < 4; j++) {
            int n = (int)n0 + wn * 64 + j * 16 + lm;
            float bv = bias[n];
#pragma unroll
            for (int r = 0; r < 4; r++) {
                int m = (int)m0 + wm * 64 + i * 16 + quad * 4 + r;
                float v = acc[i][j][r] + bv;
                if (relu) v = fmaxf(v, 0.f);
                if (Cf) Cf[(long)m * N + n] = v;
                if (Cb) Cb[(long)m * N + n] = f2bf(v);
            }
        }
    }
}

// ---------------------------------------------------------------- bf16 MFMA GEMM, 64x128 tile (async LDS)
__global__ __launch_bounds__(256) void gemm_mfma_bt64_kernel(
    const ushort* __restrict__ A, const ushort* __restrict__ Bt,
    const float* __restrict__ bias, float* __restrict__ Cf, ushort* __restrict__ Cb,
    int M, int N, int K, int relu)
{
    __shared__ ushort As[64 * 32];
    __shared__ ushort Bs[128 * 32];
    int t = threadIdx.x;
    int w = t >> 6, l = t & 63;
    int quad = l >> 4, lm = l & 15;
    int wm = w >> 1, wn = w & 1;
    long m0 = blockIdx.y * 64L;
    long n0 = blockIdx.x * 128L;
    int lr = t >> 2;
    int lk = (t & 3) * 8;
    f32x4 acc[2][4];
#pragma unroll
    for (int i = 0; i < 2; i++)
#pragma unroll
        for (int j = 0; j < 4; j++) acc[i][j] = (f32x4){0.f, 0.f, 0.f, 0.f};

    for (int k0 = 0; k0 < K; k0 += 32) {
        __syncthreads();
        gl2lds16(A + (m0 + lr) * K + k0 + lk, &As[lr * 32 + lk]);
        gl2lds16(Bt + (n0 + lr) * K + k0 + lk, &Bs[lr * 32 + lk]);
        gl2lds16(Bt + (n0 + 64 + lr) * K + k0 + lk, &Bs[(64 + lr) * 32 + lk]);
        __syncthreads();
        short8 af[2], bfr[4];
#pragma unroll
        for (int i = 0; i < 2; i++)
            af[i] = *(const short8*)&As[(wm * 32 + i * 16 + lm) * 32 + quad * 8];
#pragma unroll
        for (int j = 0; j < 4; j++)
            bfr[j] = *(const short8*)&Bs[(wn * 64 + j * 16 + lm) * 32 + quad * 8];
#pragma unroll
        for (int i = 0; i < 2; i++)
#pragma unroll
            for (int j = 0; j < 4; j++)
                acc[i][j] = __builtin_amdgcn_mfma_f32_16x16x32_bf16(af[i], bfr[j], acc[i][j], 0, 0, 0);
    }
#pragma unroll
    for (int i = 0; i < 2; i++) {
#pragma unroll
        for (int j = 0; j < 4; j++) {
            int n = (int)n0 + wn * 64 + j * 16 + lm;
            float bv = bias[n];
#pragma unroll
            for (int r = 0; r < 4; r++) {
                int m = (int)m0 + wm * 32 + i * 16 + quad * 4 + r;
                float v = acc[i][j][r] + bv;
                if (relu) v = fmaxf(v, 0.f);
                if (Cf) Cf[(long)m * N + n] = v;
                if (Cb) Cb[(long)m * N + n] = f2bf(v);
            }
        }
    }
}

// ---------------------------------------------------------------- bf16 MFMA GEMM, 64x128 tile, XCD-panel swizzle
// 1D grid; CB = column-blocks per A row-panel (N/128). All CB col-blocks of a row-panel are mapped to
// the SAME XCD (xcd = L%8 round-robin assumption, T1/HK chiplet pattern) so the A panel is fetched into
// that XCD's L2 once and reused CB times. Requires gridDim.x % (8*CB) == 0.
__global__ __launch_bounds__(256) void gemm_mfma_bt64x_kernel(
    const ushort* __restrict__ A, const ushort* __restrict__ Bt,
    const float* __restrict__ bias, float* __restrict__ Cf, ushort* __restrict__ Cb,
    int M, int N, int K, int relu, int CB)
{
    __shared__ ushort As[64 * 32];
    __shared__ ushort Bs[128 * 32];
    int L = blockIdx.x;
    int xcd = L & 7;
    int slot = L >> 3;
    int ppx = (int)gridDim.x / (8 * CB);    // panels per XCD
    int panel = xcd * ppx + slot / CB;
    int col = slot % CB;
    int t = threadIdx.x;
    int w = t >> 6, l = t & 63;
    int quad = l >> 4, lm = l & 15;
    int wm = w >> 1, wn = w & 1;
    long m0 = panel * 64L;
    long n0 = col * 128L;
    int lr = t >> 2;
    int lk = (t & 3) * 8;
    f32x4 acc[2][4];
#pragma unroll
    for (int i = 0; i < 2; i++)
#pragma unroll
        for (int j = 0; j < 4; j++) acc[i][j] = (f32x4){0.f, 0.f, 0.f, 0.f};

    for (int k0 = 0; k0 < K; k0 += 32) {
        __syncthreads();
        gl2lds16(A + (m0 + lr) * K + k0 + lk, &As[lr * 32 + lk]);
        gl2lds16(Bt + (n0 + lr) * K + k0 + lk, &Bs[lr * 32 + lk]);
        gl2lds16(Bt + (n0 + 64 + lr) * K + k0 + lk, &Bs[(64 + lr) * 32 + lk]);
        __syncthreads();
        short8 af[2], bfr[4];
#pragma unroll
        for (int i = 0; i < 2; i++)
            af[i] = *(const short8*)&As[(wm * 32 + i * 16 + lm) * 32 + quad * 8];
#pragma unroll
        for (int j = 0; j < 4; j++)
            bfr[j] = *(const short8*)&Bs[(wn * 64 + j * 16 + lm) * 32 + quad * 8];
#pragma unroll
        for (int i = 0; i < 2; i++)
#pragma unroll
            for (int j = 0; j < 4; j++)
                acc[i][j] = __builtin_amdgcn_mfma_f32_16x16x32_bf16(af[i], bfr[j], acc[i][j], 0, 0, 0);
    }
#pragma unroll
    for (int i = 0; i < 2; i++) {
#pragma unroll
        for (int j = 0; j < 4; j++) {
            int n = (int)n0 + wn * 64 + j * 16 + lm;
            float bv = bias[n];
#pragma unroll
            for (int r = 0; r < 4; r++) {
                int m = (int)m0 + wm * 32 + i * 16 + quad * 4 + r;
                float v = acc[i][j][r] + bv;
                if (relu) v = fmaxf(v, 0.f);
                if (Cf) Cf[(long)m * N + n] = v;
                if (Cb) Cb[(long)m * N + n] = f2bf(v);
            }
        }
    }
}

// ---------------------------------------------------------------- bf16 MFMA GEMM, 64x64 tile (async LDS)
__global__ __launch_bounds__(256) void gemm_mfma_bt6464_kernel(
    const ushort* __restrict__ A, const ushort* __restrict__ Bt,
    const float* __restrict__ bias, float* __restrict__ Cf, ushort* __restrict__ Cb,
    int M, int N, int K, int relu)
{
    __shared__ ushort As[64 * 32];
    __shared__ ushort Bs[64 * 32];
    int t = threadIdx.x;
    int w = t >> 6, l = t & 63;
    int quad = l >> 4, lm = l & 15;
    int wm = w >> 1, wn = w & 1;
    long m0 = blockIdx.y * 64L;
    long n0 = blockIdx.x * 64L;
    int lr = t >> 2;
    int lk = (t & 3) * 8;
    f32x4 acc[2][2];
#pragma unroll
    for (int i = 0; i < 2; i++)
#pragma unroll
        for (int j = 0; j < 2; j++) acc[i][j] = (f32x4){0.f, 0.f, 0.f, 0.f};

    for (int k0 = 0; k0 < K; k0 += 32) {
        __syncthreads();
        gl2lds16(A + (m0 + lr) * K + k0 + lk, &As[lr * 32 + lk]);
        gl2lds16(Bt + (n0 + lr) * K + k0 + lk, &Bs[lr * 32 + lk]);
        __syncthreads();
        short8 af[2], bfr[2];
#pragma unroll
        for (int i = 0; i < 2; i++)
            af[i] = *(const short8*)&As[(wm * 32 + i * 16 + lm) * 32 + quad * 8];
#pragma unroll
        for (int j = 0; j < 2; j++)
            bfr[j] = *(const short8*)&Bs[(wn * 32 + j * 16 + lm) * 32 + quad * 8];
#pragma unroll
        for (int i = 0; i < 2; i++)
#pragma unroll
            for (int j = 0; j < 2; j++)
                acc[i][j] = __builtin_amdgcn_mfma_f32_16x16x32_bf16(af[i], bfr[j], acc[i][j], 0, 0, 0);
    }
#pragma unroll
    for (int i = 0; i < 2; i++) {
#pragma unroll
        for (int j = 0; j < 2; j++) {
            int n = (int)n0 + wn * 32 + j * 16 + lm;
            float bv = bias[n];
#pragma unroll
            for (int r = 0; r < 4; r++) {
                int m = (int)m0 + wm * 32 + i * 16 + quad * 4 + r;
                float v = acc[i][j][r] + bv;
                if (relu) v = fmaxf(v, 0.f);
                if (Cf) Cf[(long)m * N + n] = v;
                if (Cb) Cb[(long)m * N + n] = f2bf(v);
            }
        }
    }
}

// ---------------------------------------------------------------- wc3 head
__global__ __launch_bounds__(256) void wc3_kernel(const float* __restrict__ h2,
                                                  const float* __restrict__ wc3t,
                                                  const float* __restrict__ bc3,
                                                  float* __restrict__ out) {
    int r8 = threadIdx.x >> 5;
    int c = threadIdx.x & 31;
    long row = blockIdx.x * 8L + r8;
    const float* hr = h2 + row * 512;
    float acc = 0.f;
    if (c < 30) {
        for (int k = 0; k < 512; k++)
            acc += hr[k] * wc3t[k * 30 + c];
        acc += bc3[c];
        if (c < 6) out[row * 6 + c] = acc;
        else       out[49152 + row * 24 + (c - 6)] = acc;
    }
}

// ---------------------------------------------------------------- fuse (row-per-block)
__global__ __launch_bounds__(256) void fuse_bf_kernel(
    const float* __restrict__ fm0, const float* __restrict__ fm1,
    const float* __restrict__ fm2, const float* __restrict__ fm3,
    const float* __restrict__ fm4, const unsigned* __restrict__ fg_enc,
    const float* __restrict__ onehot,
    const int* __restrict__ n1, const int* __restrict__ n2,
    ushort* __restrict__ fuse_b, float* __restrict__ feat) {
    long row = blockIdx.x;
    int b = (int)(row >> 11);
    int i1 = n1[row], i2 = n2[row];
    const float* p0 = fm0 + row * 128;
    const float* p1 = fm1 + row * 128;
    const float* p2 = fm2 + ((long)b * 512 + i1) * 256;
    const float* p3 = fm3 + ((long)b * 512 + i1) * 256;
    const float* p4 = fm4 + ((long)b * 128 + i2) * 512;
    const unsigned* pg = fg_enc + b * 512;
    const float* po = onehot + b * 16;
    ushort* fb = fuse_b + row * 1824;
    float* ft = feat + row * 1296;
#pragma unroll
    for (int k = 0; k < 8; k++) {
        int c = threadIdx.x + k * 256;
        if (c >= 1824) break;
        float val = 0.f;
        if (c < 128)       val = p0[c];
        else if (c < 256)  val = p1[c - 128];
        else if (c < 512)  val = p2[c - 256];
        else if (c < 768)  val = p3[c - 512];
        else if (c < 1280) val = p4[c - 768];
        else if (c < 1792) val = fdec(pg[c - 1280]);
        else if (c < 1808) val = po[c - 1792];
        fb[c] = f2bf(val);
        if (c < 1280)                   ft[c] = val;
        else if (c >= 1792 && c < 1808) ft[c - 512] = val;
    }
}

// ---------------------------------------------------------------- launch

extern "C" void kernel_launch(void* const* d_in, const int* in_sizes, int n_in,
                              void* d_out, int out_size, void* d_ws, size_t ws_size,
                              hipStream_t stream) {
    const float* verts  = (const float*)d_in[0];
    const float* onehot = (const float*)d_in[1];
    const float* dir0 = (const float*)d_in[2];
    const float* w1 = (const float*)d_in[3];
    const float* b1 = (const float*)d_in[4];
    const float* dir1 = (const float*)d_in[5];
    const float* w2 = (const float*)d_in[6];
    const float* b2 = (const float*)d_in[7];
    const float* dir2 = (const float*)d_in[8];
    const float* w3 = (const float*)d_in[9];
    const float* b3 = (const float*)d_in[10];
    const float* dir3 = (const float*)d_in[11];
    const float* w4 = (const float*)d_in[12];
    const float* b4 = (const float*)d_in[13];
    const float* dir4 = (const float*)d_in[14];
    const float* g_bn1 = (const float*)d_in[15];
    const float* be_bn1 = (const float*)d_in[16];
    const float* g_bn2 = (const float*)d_in[17];
    const float* be_bn2 = (const float*)d_in[18];
    const float* g_bn3 = (const float*)d_in[19];
    const float* be_bn3 = (const float*)d_in[20];
    const float* wc1 = (const float*)d_in[21];
    const float* bc1 = (const float*)d_in[22];
    const float* wc2 = (const float*)d_in[23];
    const float* bc2 = (const float*)d_in[24];
    const float* wc3 = (const float*)d_in[25];
    const float* bc3 = (const float*)d_in[26];
    float* outf = (float*)d_out;

    float* wsf = (float*)d_ws;
    size_t off = 0;
    auto alloc = [&](size_t n) { float* p = wsf + off; off += (n + 15) & ~(size_t)15; return p; };

    float* sd0 = alloc(3 * 896);
    float* sd1 = alloc(3 * 896);
    float* sd2 = alloc(3 * 1792);
    float* sd3 = alloc(3 * 1792);
    float* sd4 = alloc(3 * 3584);
    float* wc3t = alloc(512L * 30);
    float* fm0 = alloc(8192L * 128);
    float* fm1 = alloc(8192L * 128);
    float* c1  = alloc(8192L * 128);
    float* fm2 = alloc(2048L * 256);
    float* c2  = alloc(2048L * 256);
    float* fm3 = alloc(2048L * 256);
    float* c3  = alloc(2048L * 256);
    float* fm4 = alloc(512L * 512);
    float* statbase = alloc(3328);
    float* stat1 = statbase;
    float* stat2 = statbase + 256;
    float* stat3 = statbase + 768;
    unsigned* fg_enc = (unsigned*)(statbase + 1280);
    float* fbuf = alloc(8192L * 1024);
    float* h2 = alloc(8192L * 512);
    float* pd  = alloc(KTOT);
    ushort* pi = (ushort*)alloc(KTOT / 2);
    int* nb   = (int*)alloc(8192L * KNB);
    int* nb1  = (int*)alloc(2048L * KNB);
    int* nb2  = (int*)alloc(512L * KNB);
    int* nbp1 = (int*)alloc(2048L * 4);
    int* nbp2 = (int*)alloc(512L * 4);
    int* n1   = (int*)alloc(8192);
    int* n2   = (int*)alloc(8192);
    ushort* fuse_b = (ushort*)alloc(8192L * 1824 / 2);
    ushort* h1b    = (ushort*)alloc(8192L * 512 / 2);
    ushort* wc1b   = (ushort*)alloc(512L * 1824 / 2);
    ushort* wc2b   = (ushort*)alloc(512L * 512 / 2);
    ushort* w1tb   = (ushort*)alloc(1024L * 128 / 2);
    ushort* w2tb   = (ushort*)alloc(2048L * 128 / 2);
    ushort* w3tb   = (ushort*)alloc(2048L * 256 / 2);
    ushort* w4tb   = (ushort*)alloc(4096L * 256 / 2);
    ushort* fm0b   = (ushort*)alloc(8192L * 128 / 2);
    ushort* fp1b   = (ushort*)alloc(2048L * 128 / 2);
    ushort* fm2b   = (ushort*)alloc(2048L * 256 / 2);
    ushort* fp2b   = (ushort*)alloc(512L * 256 / 2);

    auto nblk = [](long n, int b) { return (unsigned)((n + b - 1) / b); };

    hipMemsetAsync(statbase, 0, 3328 * sizeof(float), stream);

    // fused front: knn partials + nearest + prep + weight transpose (mutually independent)
    front_uber<<<1088 + PREP_BLOCKS + 1920, 256, 0, stream>>>(
        verts, pd, pi, n1, n2,
        dir0, dir1, dir2, dir3, dir4, sd0, sd1, sd2, sd3, sd4,
        wc3, wc3t, wc1, wc1b, wc2, wc2b,
        w1, w2, w3, w4, w1tb, w2tb, w3tb, w4tb);

    knn_merge_uber<<<2184, 256, 0, stream>>>(pd, pi, nb, nb1, nb2, nbp1, nbp2);

    conv_surface_kernel<<<BSZ * 2048, 128, 0, stream>>>(verts, nb, sd0, fm0, fm0b);

    // layer1 (M=8192, N=1024, K=128)
    gemm_mfma_bt_kernel<<<dim3(8, 64), 256, 0, stream>>>(fm0b, w1tb, b1, fbuf, nullptr, 8192, 1024, 128, 0);
    conv_act_kernel<<<BSZ * 2048, 128, 0, stream>>>(verts, nb, sd1, fbuf, c1, nullptr, 2048, 128);
    bn_stat_kernel<<<256, 256, 0, stream>>>(c1, stat1, 8192, 128);
    bn_apply_relu_kernel<<<nblk(8192L * 128, 256), 256, 0, stream>>>(c1, stat1, g_bn1, be_bn1, fm1, nullptr, 8192, 128);

    pool_b_kernel<<<nblk(BSZ * 512L * 128, 256), 256, 0, stream>>>(fm1, nbp1, fp1b, 2048, 512, 128);

    // layer2 (M=2048, N=2048, K=128)
    gemm_mfma_bt64_kernel<<<dim3(16, 32), 256, 0, stream>>>(fp1b, w2tb, b2, fbuf, nullptr, 2048, 2048, 128, 0);
    conv_act_kernel<<<BSZ * 512, 256, 0, stream>>>(verts, nb1, sd2, fbuf, c2, nullptr, 512, 256);
    bn_stat_kernel<<<256, 256, 0, stream>>>(c2, stat2, 2048, 256);
    bn_apply_relu_kernel<<<nblk(2048L * 256, 256), 256, 0, stream>>>(c2, stat2, g_bn2, be_bn2, fm2, fm2b, 2048, 256);

    // layer3 (M=2048, N=2048, K=256)
    gemm_mfma_bt64_kernel<<<dim3(16, 32), 256, 0, stream>>>(fm2b, w3tb, b3, fbuf, nullptr, 2048, 2048, 256, 0);
    conv_act_kernel<<<BSZ * 512, 256, 0, stream>>>(verts, nb1, sd3, fbuf, c3, nullptr, 512, 256);
    bn_stat_kernel<<<256, 256, 0, stream>>>(c3, stat3, 2048, 256);
    bn_apply_relu_kernel<<<nblk(2048L * 256, 256), 256, 0, stream>>>(c3, stat3, g_bn3, be_bn3, fm3, nullptr, 2048, 256);

    pool_b_kernel<<<nblk(BSZ * 128L * 256, 256), 256, 0, stream>>>(fm3, nbp2, fp2b, 512, 128, 256);

    // layer4 (M=512, N=4096, K=256) -- 64x64 tile: 512 blocks (2/CU)
    gemm_mfma_bt6464_kernel<<<dim3(64, 8), 256, 0, stream>>>(fp2b, w4tb, b4, fbuf, nullptr, 512, 4096, 256, 0);
    conv_act_kernel<<<BSZ * 128, 512, 0, stream>>>(verts, nb2, sd4, fbuf, fm4, fg_enc, 128, 512);

    // fuse -> bf16 GEMM input + fp32 feat (direct to d_out)
    fuse_bf_kernel<<<8192, 256, 0, stream>>>(fm0, fm1, fm2, fm3, fm4, fg_enc, onehot,
                                             n1, n2, fuse_b, outf + 245760);

    // MLP head (M=8192, N=512) -- 64x128 tile + XCD-panel swizzle (CB=4 col-blocks share A panel per XCD)
    gemm_mfma_bt64x_kernel<<<512, 256, 0, stream>>>(fuse_b, wc1b, bc1, nullptr, h1b, 8192, 512, 1824, 1, 4);
    gemm_mfma_bt64x_kernel<<<512, 256, 0, stream>>>(h1b, wc2b, bc2, h2, nullptr, 8192, 512, 512, 1, 4);
    wc3_kernel<<<1024, 256, 0, stream>>>(h2, wc3t, bc3, outf);
}

// Round 12
// 442.353 us; speedup vs baseline: 1.0408x; 1.0303x over previous
//
#include <hip/hip_runtime.h>
#include <hip/hip_bf16.h>
#include <math.h>

#define BSZ 4
#define VN 2048
#define SS 7
#define KNB 10

typedef __attribute__((ext_vector_type(8))) short short8;
typedef __attribute__((ext_vector_type(4))) float f32x4;
typedef __attribute__((address_space(1))) const void gcvoid;
typedef __attribute__((address_space(3))) void lvoid;

__device__ inline ushort f2bf(float x) {
    __hip_bfloat16 h = __float2bfloat16(x);
    return *(ushort*)&h;
}

__device__ inline void gl2lds16(const ushort* g, ushort* l) {
    __builtin_amdgcn_global_load_lds((gcvoid*)g, (lvoid*)l, 16, 0, 0);
}

__device__ inline unsigned fenc(float f) {
    unsigned b = __float_as_uint(f);
    return (b & 0x80000000u) ? ~b : (b | 0x80000000u);
}
__device__ inline float fdec(unsigned e) {
    unsigned b = (e & 0x80000000u) ? (e & 0x7FFFFFFFu) : ~e;
    return __uint_as_float(b);
}

#define INS(dq, iq, dd, jj) { bool lt_ = (dd) < (dq); \
    float dmn_ = lt_ ? (dd) : (dq); float dmx_ = lt_ ? (dq) : (dd); \
    int imn_ = lt_ ? (jj) : (iq); int imx_ = lt_ ? (iq) : (jj); \
    (dq) = dmn_; (iq) = imn_; (dd) = dmx_; (jj) = imx_; }

// ---------------------------------------------------------------- prep (device fn; part of front_uber)
#define PB0 8960L
#define PB1 24320L
#define PB2 958208L
#define PB3 1220352L
#define PREP_BLOCKS 4767        // PB3 / 256

__device__ void prep_dev(int gb,
                         const float* __restrict__ d0, const float* __restrict__ d1,
                         const float* __restrict__ d2, const float* __restrict__ d3,
                         const float* __restrict__ d4,
                         float* __restrict__ s0, float* __restrict__ s1,
                         float* __restrict__ s2, float* __restrict__ s3, float* __restrict__ s4,
                         const float* __restrict__ wc3, float* __restrict__ wc3t,
                         const float* __restrict__ wc1, ushort* __restrict__ wc1b,
                         const float* __restrict__ wc2, ushort* __restrict__ wc2b) {
    long i = gb * 256L + threadIdx.x;
    if (i < PB0) {
        const float* src; float* dst; int C, c;
        if (i < 896)        { src = d0; dst = s0; C = 896;  c = (int)i; }
        else if (i < 1792)  { src = d1; dst = s1; C = 896;  c = (int)i - 896; }
        else if (i < 3584)  { src = d2; dst = s2; C = 1792; c = (int)i - 1792; }
        else if (i < 5376)  { src = d3; dst = s3; C = 1792; c = (int)i - 3584; }
        else                { src = d4; dst = s4; C = 3584; c = (int)i - 5376; }
        float a = src[c], b = src[C + c], e = src[2 * C + c];
        float den = fmaxf(sqrtf(a * a + b * b + e * e), 1e-12f);
        dst[c] = a / den; dst[C + c] = b / den; dst[2 * C + c] = e / den;
    } else if (i < PB1) {
        long j = i - PB0;
        int o = (int)(j / 512), k = (int)(j % 512);
        wc3t[(long)k * 30 + o] = wc3[j];
    } else if (i < PB2) {
        long j = i - PB1;
        int c = (int)(j % 1824);
        long r = j / 1824;
        wc1b[j] = f2bf(c < 1808 ? wc1[r * 1808 + c] : 0.f);
    } else if (i < PB3) {
        long j = i - PB2;
        wc2b[j] = f2bf(wc2[j]);
    }
}

// ---------------------------------------------------------------- weight transpose (device fn; part of front_uber)
__device__ void wt_trans_dev(int gb, float* tilef,
                             const float* __restrict__ w1, const float* __restrict__ w2,
                             const float* __restrict__ w3, const float* __restrict__ w4,
                             ushort* __restrict__ o1, ushort* __restrict__ o2,
                             ushort* __restrict__ o3, ushort* __restrict__ o4) {
    const float* w; ushort* o; int K, N, t;
    if (gb < 128)      { w = w1; o = o1; K = 128; N = 1024; t = gb; }
    else if (gb < 384) { w = w2; o = o2; K = 128; N = 2048; t = gb - 128; }
    else if (gb < 896) { w = w3; o = o3; K = 256; N = 2048; t = gb - 384; }
    else               { w = w4; o = o4; K = 256; N = 4096; t = gb - 896; }
    int tn = t % (N / 32), tk = t / (N / 32);
    int n0 = tn * 32, k0 = tk * 32;
    int tx = threadIdx.x % 32, ty = threadIdx.x / 32;
#pragma unroll
    for (int r = 0; r < 32; r += 8)
        tilef[(ty + r) * 33 + tx] = w[(long)(k0 + ty + r) * N + n0 + tx];
    __syncthreads();
#pragma unroll
    for (int r = 0; r < 32; r += 8)
        o[(long)(n0 + ty + r) * K + k0 + tx] = f2bf(tilef[tx * 33 + ty + r]);
}

// ---------------------------------------------------------------- knn part (exact fp32, 64-source chunks)
// Only the 2048x2048 pass is computed: pooled point sets vp1/vp2 are PREFIXES of vertices
// (verts[:, :512], verts[:, :128]), so their partial lists are sub-slices of the big run.
// per target, per 64-source chunk: 2 sorted 10-lists (sublists of 32 sources, ascending index ranges)
// pd[ ((b*2048 + i)*32 + ch)*20 + l*10 + q ] == row (b*2048+i), list c=2*ch+l at (row*64+c)*10
#define KTOT  5242880L

__device__ void knn_part_dev(const float* __restrict__ verts, int T, int nch,
                             int tile, int b, int ch,
                             float* __restrict__ pd, ushort* __restrict__ pi,
                             float4* __restrict__ s4) {
    const float* vb = verts + (long)b * VN * 3;
    int j0 = ch * 64;
    for (int j = threadIdx.x; j < 64; j += 256) {
        float x = vb[(j0 + j) * 3 + 0];
        float y = vb[(j0 + j) * 3 + 1];
        float z = vb[(j0 + j) * 3 + 2];
        s4[j] = make_float4(x, y, z, x * x + y * y + z * z);
    }
    __syncthreads();
    int i = tile * 256 + (int)threadIdx.x;
    if (i >= T) return;
    float px = vb[i * 3], py = vb[i * 3 + 1], pz = vb[i * 3 + 2];
    float d0[10], d1[10];
    int id0[10], id1[10];
#pragma unroll
    for (int q = 0; q < 10; q++) {
        d0[q] = 1e30f; d1[q] = 1e30f;
        id0[q] = 0; id1[q] = 0;
    }
    for (int j = 0; j < 32; j++) {
        float4 sA = s4[j];
        float4 sB = s4[32 + j];
        float dA = fmaf(-2.f, px * sA.x + py * sA.y + pz * sA.z, sA.w);
        float dB = fmaf(-2.f, px * sB.x + py * sB.y + pz * sB.z, sB.w);
        int jA = j0 + j, jB = j0 + 32 + j;
        dA = (jA == i) ? 1e30f : dA;
        dB = (jB == i) ? 1e30f : dB;
#pragma unroll
        for (int q = 0; q < 10; q++) { INS(d0[q], id0[q], dA, jA); }
#pragma unroll
        for (int q = 0; q < 10; q++) { INS(d1[q], id1[q], dB, jB); }
    }
    long base = ((long)(b * T + i) * nch + ch) * 20;
    // vectorized stores: base is a multiple of 20 floats (80B) -> list0 16B-aligned, list1 (+40B) 8B-aligned
    *(float4*)(pd + base)      = make_float4(d0[0], d0[1], d0[2], d0[3]);
    *(float4*)(pd + base + 4)  = make_float4(d0[4], d0[5], d0[6], d0[7]);
    *(float2*)(pd + base + 8)  = make_float2(d0[8], d0[9]);
    *(float2*)(pd + base + 10) = make_float2(d1[0], d1[1]);
    *(float2*)(pd + base + 12) = make_float2(d1[2], d1[3]);
    *(float2*)(pd + base + 14) = make_float2(d1[4], d1[5]);
    *(float2*)(pd + base + 16) = make_float2(d1[6], d1[7]);
    *(float2*)(pd + base + 18) = make_float2(d1[8], d1[9]);
    // index pairs packed little-endian u16|u16<<16 == the u32 words the merge reads
    uint* pu = (uint*)(pi + base);
#pragma unroll
    for (int q = 0; q < 5; q++)
        pu[q] = (uint)(ushort)id0[2 * q] | ((uint)(ushort)id0[2 * q + 1] << 16);
#pragma unroll
    for (int q = 0; q < 5; q++)
        pu[5 + q] = (uint)(ushort)id1[2 * q] | ((uint)(ushort)id1[2 * q + 1] << 16);
}

__device__ void nearest_dev(const float* __restrict__ verts, int SN, int* __restrict__ out,
                            int gl, float4* __restrict__ s4) {
    int t = gl * 256 + (int)threadIdx.x;
    int b = t / VN;
    const float* vb = verts + (long)b * VN * 3;
    for (int j = threadIdx.x; j < SN; j += 256) {
        float x = vb[j * 3], y = vb[j * 3 + 1], z = vb[j * 3 + 2];
        s4[j] = make_float4(x, y, z, x * x + y * y + z * z);
    }
    __syncthreads();
    int i = t % VN;
    float px = vb[i * 3], py = vb[i * 3 + 1], pz = vb[i * 3 + 2];
    int h = SN / 2;
    float b0 = 1e30f, b1 = 1e30f; int i0 = 0, i1 = 0;
    for (int j = 0; j < h; j++) {
        float4 sA = s4[j];
        float4 sB = s4[h + j];
        float dA = fmaf(-2.f, px * sA.x + py * sA.y + pz * sA.z, sA.w);
        float dB = fmaf(-2.f, px * sB.x + py * sB.y + pz * sB.z, sB.w);
        bool lA = dA < b0; b0 = lA ? dA : b0; i0 = lA ? j : i0;
        bool lB = dB < b1; b1 = lB ? dB : b1; i1 = lB ? (h + j) : i1;
    }
    out[t] = (b1 < b0) ? i1 : i0;
}

// ---------------------------------------------------------------- front uber: knn part + nearest + prep + weight transpose
//  [0,1024)        knn big: 8 tiles x (4 b x 32 ch)   2048x2048
//  [1024,1056)     nearest n1 (512 sources)
//  [1056,1088)     nearest n2 (128 sources)
//  [1088,5855)     prep (4767 blocks)
//  [5855,7775)     weight transpose (1920 blocks)
__global__ __launch_bounds__(256) void front_uber(const float* __restrict__ verts,
                                                  float* __restrict__ pd, ushort* __restrict__ pi,
                                                  int* __restrict__ n1, int* __restrict__ n2,
                                                  const float* __restrict__ d0, const float* __restrict__ d1,
                                                  const float* __restrict__ d2, const float* __restrict__ d3,
                                                  const float* __restrict__ d4,
                                                  float* __restrict__ s0, float* __restrict__ s1,
                                                  float* __restrict__ s2, float* __restrict__ s3,
                                                  float* __restrict__ s4v,
                                                  const float* __restrict__ wc3, float* __restrict__ wc3t,
                                                  const float* __restrict__ wc1, ushort* __restrict__ wc1b,
                                                  const float* __restrict__ wc2, ushort* __restrict__ wc2b,
                                                  const float* __restrict__ w1, const float* __restrict__ w2,
                                                  const float* __restrict__ w3, const float* __restrict__ w4,
                                                  ushort* __restrict__ o1, ushort* __restrict__ o2,
                                                  ushort* __restrict__ o3, ushort* __restrict__ o4) {
    __shared__ float4 smem[512];        // knn/nearest: float4[512]; trans: float[32][33] alias
    int gb = blockIdx.x;
    if (gb < 1024) {
        int tile = gb & 7, bc = gb >> 3;
        knn_part_dev(verts, 2048, 32, tile, bc >> 5, bc & 31, pd, pi, smem);
    } else if (gb < 1056) {
        nearest_dev(verts, 512, n1, gb - 1024, smem);
    } else if (gb < 1088) {
        nearest_dev(verts, 128, n2, gb - 1056, smem);
    } else if (gb < 1088 + PREP_BLOCKS) {
        prep_dev(gb - 1088, d0, d1, d2, d3, d4, s0, s1, s2, s3, s4v,
                 wc3, wc3t, wc1, wc1b, wc2, wc2b);
    } else {
        wt_trans_dev(gb - (1088 + PREP_BLOCKS), (float*)smem, w1, w2, w3, w4, o1, o2, o3, o4);
    }
}

// ---------------------------------------------------------------- knn selection: lane-per-list tournament
template <int G>
__device__ void knn_sel_dev(const float* __restrict__ pd, const ushort* __restrict__ pi,
                            int blk, int Tsub, int* __restrict__ out,
                            int* __restrict__ outp, int Tp) {
    typedef unsigned long long u64;
    constexpr int TPB = 256 / G;        // targets per block
    int tid = threadIdx.x;
    long t = (long)blk * TPB + (tid / G);
    int c = tid % G;
    int bb = (int)(t / Tsub), ii = (int)(t % Tsub);
    long row = (long)bb * 2048 + ii;
    long base = (row * 64 + c) * 10;
    const float2* pf = (const float2*)(pd + base);   // 40B stride -> 8B aligned
    const uint*   pu = (const uint*)(pi + base);     // 20B stride -> 4B aligned
    float2 f0 = pf[0], f1 = pf[1], f2 = pf[2], f3 = pf[3], f4 = pf[4];
    uint   u0 = pu[0], u1 = pu[1], u2 = pu[2], u3 = pu[3], u4 = pu[4];
    u64 k0 = ((u64)fenc(f0.x) << 32) | (u0 & 0xFFFFu);
    u64 k1 = ((u64)fenc(f0.y) << 32) | (u0 >> 16);
    u64 k2 = ((u64)fenc(f1.x) << 32) | (u1 & 0xFFFFu);
    u64 k3 = ((u64)fenc(f1.y) << 32) | (u1 >> 16);
    u64 k4 = ((u64)fenc(f2.x) << 32) | (u2 & 0xFFFFu);
    u64 k5 = ((u64)fenc(f2.y) << 32) | (u2 >> 16);
    u64 k6 = ((u64)fenc(f3.x) << 32) | (u3 & 0xFFFFu);
    u64 k7 = ((u64)fenc(f3.y) << 32) | (u3 >> 16);
    u64 k8 = ((u64)fenc(f4.x) << 32) | (u4 & 0xFFFFu);
    u64 k9 = ((u64)fenc(f4.y) << 32) | (u4 >> 16);
    bool wp = (outp != nullptr) && (ii < Tp);
#pragma unroll
    for (int q = 0; q < 10; q++) {
        u64 m = k0;
#pragma unroll
        for (int s = 1; s < G; s <<= 1) {
            u64 o = (u64)__shfl_xor((long long)m, s);
            m = (o < m) ? o : m;
        }
        if (c == 0) {
            int idx = (int)(unsigned)(m & 0xFFFFFFFFull);
            out[t * 10 + q] = idx;
            if (wp && q < 4) outp[((long)bb * Tp + ii) * 4 + q] = idx;
        }
        if (k0 == m) {
            k0 = k1; k1 = k2; k2 = k3; k3 = k4; k4 = k5;
            k5 = k6; k6 = k7; k7 = k8; k8 = k9;
            k9 = 0xFFFFFFFFFFFFFFFFull;
        }
    }
}

// grid: [0,2048) big (8192 t, 64 lists, 4 t/blk) | [2048,2176) mid (2048 t, 16 lists, 16 t/blk)
//       | [2176,2184) small (512 t, 4 lists, 64 t/blk)
__global__ __launch_bounds__(256) void knn_merge_uber(const float* __restrict__ pd, const ushort* __restrict__ pi,
                                                      int* __restrict__ nb, int* __restrict__ nb1,
                                                      int* __restrict__ nb2, int* __restrict__ nbp1,
                                                      int* __restrict__ nbp2) {
    int gb = blockIdx.x;
    if (gb < 2048)      knn_sel_dev<64>(pd, pi, gb, 2048, nb, nbp1, 512);
    else if (gb < 2176) knn_sel_dev<16>(pd, pi, gb - 2048, 512, nb1, nbp2, 128);
    else                knn_sel_dev<4>(pd, pi, gb - 2176, 128, nb2, nullptr, 1);
}

// ---------------------------------------------------------------- conv_surface (fp32 + bf16 out)
__global__ void conv_surface_kernel(const float* __restrict__ verts, const int* __restrict__ nb,
                                    const float* __restrict__ sd, float* __restrict__ fm0,
                                    ushort* __restrict__ fm0b) {
    int bv = blockIdx.x;
    int b = bv / VN, v = bv % VN;
    __shared__ float snd[KNB][3];
    int tid = threadIdx.x;
    if (tid < KNB) {
        int nj = nb[(long)bv * KNB + tid];
        const float* vb = verts + (long)b * VN * 3;
        float dx = vb[nj * 3] - vb[v * 3];
        float dy = vb[nj * 3 + 1] - vb[v * 3 + 1];
        float dz = vb[nj * 3 + 2] - vb[v * 3 + 2];
        float den = fmaxf(sqrtf(dx * dx + dy * dy + dz * dz), 1e-12f);
        snd[tid][0] = dx / den; snd[tid][1] = dy / den; snd[tid][2] = dz / den;
    }
    __syncthreads();
    int c = tid;
    float acc = 0.f;
#pragma unroll
    for (int s = 0; s < SS; s++) {
        int col = s * 128 + c;
        float s0 = sd[col], s1 = sd[896 + col], s2 = sd[2 * 896 + col];
        float m = 0.f;
#pragma unroll
        for (int n = 0; n < KNB; n++) {
            float dot = snd[n][0] * s0 + snd[n][1] * s1 + snd[n][2] * s2;
            m = fmaxf(m, dot);
        }
        acc += m;
    }
    fm0[(long)bv * 128 + c] = acc;
    fm0b[(long)bv * 128 + c] = f2bf(acc);
}

// ---------------------------------------------------------------- conv_layer act (+opt fg max)
// s-loop fully unrolled: all 70 (s,n) gather loads are independent -> issue together for latency hiding
__global__ void conv_act_kernel(const float* __restrict__ verts, const int* __restrict__ nb,
                                const float* __restrict__ sd, const float* __restrict__ fo,
                                float* __restrict__ out, unsigned* __restrict__ fgmax,
                                int Vl, int outC) {
    int bv = blockIdx.x;
    int b = bv / Vl, v = bv % Vl;
    __shared__ float snd[KNB][3];
    __shared__ int srow[KNB];
    int tid = threadIdx.x;
    if (tid < KNB) {
        int nj = nb[(long)bv * KNB + tid];
        srow[tid] = b * Vl + nj;
        const float* vb = verts + (long)b * VN * 3;
        float dx = vb[nj * 3] - vb[v * 3];
        float dy = vb[nj * 3 + 1] - vb[v * 3 + 1];
        float dz = vb[nj * 3 + 2] - vb[v * 3 + 2];
        float den = fmaxf(sqrtf(dx * dx + dy * dy + dz * dz), 1e-12f);
        snd[tid][0] = dx / den; snd[tid][1] = dy / den; snd[tid][2] = dz / den;
    }
    __syncthreads();
    int c = tid;
    int SC = SS * outC;
    int foN = SC + outC;
    float acc = fo[(long)bv * foN + c];
#pragma unroll
    for (int s = 0; s < SS; s++) {
        int col = s * outC + c;
        float s0 = sd[col], s1 = sd[SC + col], s2 = sd[2 * SC + col];
        float m = -1e30f;
#pragma unroll
        for (int n = 0; n < KNB; n++) {
            float dot = snd[n][0] * s0 + snd[n][1] * s1 + snd[n][2] * s2;
            float th = fmaxf(dot, 0.f);
            float sup = fo[(long)srow[n] * foN + outC + col];
            m = fmaxf(m, th * sup);
        }
        acc += m;
    }
    out[(long)bv * outC + c] = acc;
    if (fgmax) atomicMax(&fgmax[b * outC + c], fenc(acc));
}

// ---------------------------------------------------------------- batchnorm stats
__global__ __launch_bounds__(256) void bn_stat_kernel(const float* __restrict__ x,
                                                      float* __restrict__ stat, int R, int C) {
    int rp = 256 / C;
    int c = threadIdx.x % C;
    int rs = threadIdx.x / C;
    float s = 0.f, s2 = 0.f;
    for (long r = (long)blockIdx.x * rp + rs; r < R; r += (long)gridDim.x * rp) {
        float v = x[r * C + c];
        s += v; s2 += v * v;
    }
    atomicAdd(&stat[c], s);
    atomicAdd(&stat[C + c], s2);
}

__global__ void bn_apply_relu_kernel(const float* __restrict__ x, const float* __restrict__ stat,
                                     const float* __restrict__ g, const float* __restrict__ be,
                                     float* __restrict__ out, ushort* __restrict__ outb, int R, int C) {
    long i = blockIdx.x * 256L + threadIdx.x;
    if (i >= (long)R * C) return;
    int c = (int)(i % C);
    float mu = stat[c] / R;
    float var = stat[C + c] / R - mu * mu;
    var = fmaxf(var, 0.f);
    float y = (x[i] - mu) * rsqrtf(var + 1e-5f) * g[c] + be[c];
    y = fmaxf(y, 0.f);
    out[i] = y;
    if (outb) outb[i] = f2bf(y);
}

// ---------------------------------------------------------------- pool -> bf16
__global__ void pool_b_kernel(const float* __restrict__ fm, const int* __restrict__ idx,
                              ushort* __restrict__ out, int Vin, int T, int C) {
    long i = blockIdx.x * 256L + threadIdx.x;
    if (i >= (long)BSZ * T * C) return;
    int c = (int)(i % C);
    long bt = i / C;
    int b = (int)(bt / T), t = (int)(bt % T);
    const int* id = idx + ((long)b * T + t) * 4;
    float m = -1e30f;
#pragma unroll
    for (int n = 0; n < 4; n++)
        m = fmaxf(m, fm[((long)b * Vin + id[n]) * C + c]);
    out[i] = f2bf(m);
}

// ---------------------------------------------------------------- bf16 MFMA GEMM, 128x128 tile (async LDS)
__global__ __launch_bounds__(256) void gemm_mfma_bt_kernel(
    const ushort* __restrict__ A, const ushort* __restrict__ Bt,
    const float* __restrict__ bias, float* __restrict__ Cf, ushort* __restrict__ Cb,
    int M, int N, int K, int relu)
{
    __shared__ ushort As[128 * 32];
    __shared__ ushort Bs[128 * 32];
    int t = threadIdx.x;
    int w = t >> 6, l = t & 63;
    int quad = l >> 4, lm = l & 15;
    int wm = w >> 1, wn = w & 1;
    long m0 = blockIdx.y * 128L;
    long n0 = blockIdx.x * 128L;
    int lr = t >> 2;
    int lk = (t & 3) * 8;
    f32x4 acc[4][4];
#pragma unroll
    for (int i = 0; i < 4; i++)
#pragma unroll
        for (int j = 0; j < 4; j++) acc[i][j] = (f32x4){0.f, 0.f, 0.f, 0.f};

    for (int k0 = 0; k0 < K; k0 += 32) {
        __syncthreads();
        gl2lds16(A + (m0 + lr) * K + k0 + lk, &As[lr * 32 + lk]);
        gl2lds16(A + (m0 + 64 + lr) * K + k0 + lk, &As[(64 + lr) * 32 + lk]);
        gl2lds16(Bt + (n0 + lr) * K + k0 + lk, &Bs[lr * 32 + lk]);
        gl2lds16(Bt + (n0 + 64 + lr) * K + k0 + lk, &Bs[(64 + lr) * 32 + lk]);
        __syncthreads();
        short8 af[4], bfr[4];
#pragma unroll
        for (int i = 0; i < 4; i++)
            af[i] = *(const short8*)&As[(wm * 64 + i * 16 + lm) * 32 + quad * 8];
#pragma unroll
        for (int j = 0; j < 4; j++)
            bfr[j] = *(const short8*)&Bs[(wn * 64 + j * 16 + lm) * 32 + quad * 8];
#pragma unroll
        for (int i = 0; i < 4; i++)
#pragma unroll
            for (int j = 0; j < 4; j++)
                acc[i][j] = __builtin_amdgcn_mfma_f32_16x16x32_bf16(af[i], bfr[j], acc[i][j], 0, 0, 0);
    }
#pragma unroll
    for (int i = 0; i < 4; i++) {
#pragma unroll
        for (int j = 0; j < 4; j++) {
            int n = (int)n0 + wn * 64 + j * 16 + lm;
            float bv = bias[n];
#pragma unroll
            for (int r = 0; r < 4; r++) {
                int m = (int)m0 + wm * 64 + i * 16 + quad * 4 + r;
                float v = acc[i][j][r] + bv;
                if (relu) v = fmaxf(v, 0.f);
                if (Cf) Cf[(long)m * N + n] = v;
                if (Cb) Cb[(long)m * N + n] = f2bf(v);
            }
        }
    }
}

// ---------------------------------------------------------------- bf16 MFMA GEMM, 64x128 tile (async LDS)
__global__ __launch_bounds__(256) void gemm_mfma_bt64_kernel(
    const ushort* __restrict__ A, const ushort* __restrict__ Bt,
    const float* __restrict__ bias, float* __restrict__ Cf, ushort* __restrict__ Cb,
    int M, int N, int K, int relu)
{
    __shared__ ushort As[64 * 32];
    __shared__ ushort Bs[128 * 32];
    int t = threadIdx.x;
    int w = t >> 6, l = t & 63;
    int quad = l >> 4, lm = l & 15;
    int wm = w >> 1, wn = w & 1;
    long m0 = blockIdx.y * 64L;
    long n0 = blockIdx.x * 128L;
    int lr = t >> 2;
    int lk = (t & 3) * 8;
    f32x4 acc[2][4];
#pragma unroll
    for (int i = 0; i < 2; i++)
#pragma unroll
        for (int j = 0; j < 4; j++) acc[i][j] = (f32x4){0.f, 0.f, 0.f, 0.f};

    for (int k0 = 0; k0 < K; k0 += 32) {
        __syncthreads();
        gl2lds16(A + (m0 + lr) * K + k0 + lk, &As[lr * 32 + lk]);
        gl2lds16(Bt + (n0 + lr) * K + k0 + lk, &Bs[lr * 32 + lk]);
        gl2lds16(Bt + (n0 + 64 + lr) * K + k0 + lk, &Bs[(64 + lr) * 32 + lk]);
        __syncthreads();
        short8 af[2], bfr[4];
#pragma unroll
        for (int i = 0; i < 2; i++)
            af[i] = *(const short8*)&As[(wm * 32 + i * 16 + lm) * 32 + quad * 8];
#pragma unroll
        for (int j = 0; j < 4; j++)
            bfr[j] = *(const short8*)&Bs[(wn * 64 + j * 16 + lm) * 32 + quad * 8];
#pragma unroll
        for (int i = 0; i < 2; i++)
#pragma unroll
            for (int j = 0; j < 4; j++)
                acc[i][j] = __builtin_amdgcn_mfma_f32_16x16x32_bf16(af[i], bfr[j], acc[i][j], 0, 0, 0);
    }
#pragma unroll
    for (int i = 0; i < 2; i++) {
#pragma unroll
        for (int j = 0; j < 4; j++) {
            int n = (int)n0 + wn * 64 + j * 16 + lm;
            float bv = bias[n];
#pragma unroll
            for (int r = 0; r < 4; r++) {
                int m = (int)m0 + wm * 32 + i * 16 + quad * 4 + r;
                float v = acc[i][j][r] + bv;
                if (relu) v = fmaxf(v, 0.f);
                if (Cf) Cf[(long)m * N + n] = v;
                if (Cb) Cb[(long)m * N + n] = f2bf(v);
            }
        }
    }
}

// ---------------------------------------------------------------- bf16 MFMA GEMM, 64x128 tile, XCD-panel swizzle
// 1D grid; CB = column-blocks per A row-panel (N/128). All CB col-blocks of a row-panel are mapped to
// the SAME XCD (xcd = L%8 round-robin assumption, T1/HK chiplet pattern) so the A panel is fetched into
// that XCD's L2 once and reused CB times. Requires gridDim.x % (8*CB) == 0.
__global__ __launch_bounds__(256) void gemm_mfma_bt64x_kernel(
    const ushort* __restrict__ A, const ushort* __restrict__ Bt,
    const float* __restrict__ bias, float* __restrict__ Cf, ushort* __restrict__ Cb,
    int M, int N, int K, int relu, int CB)
{
    __shared__ ushort As[64 * 32];
    __shared__ ushort Bs[128 * 32];
    int L = blockIdx.x;
    int xcd = L & 7;
    int slot = L >> 3;
    int ppx = (int)gridDim.x / (8 * CB);    // panels per XCD
    int panel = xcd * ppx + slot / CB;
    int col = slot % CB;
    int t = threadIdx.x;
    int w = t >> 6, l = t & 63;
    int quad = l >> 4, lm = l & 15;
    int wm = w >> 1, wn = w & 1;
    long m0 = panel * 64L;
    long n0 = col * 128L;
    int lr = t >> 2;
    int lk = (t & 3) * 8;
    f32x4 acc[2][4];
#pragma unroll
    for (int i = 0; i < 2; i++)
#pragma unroll
        for (int j = 0; j < 4; j++) acc[i][j] = (f32x4){0.f, 0.f, 0.f, 0.f};

    for (int k0 = 0; k0 < K; k0 += 32) {
        __syncthreads();
        gl2lds16(A + (m0 + lr) * K + k0 + lk, &As[lr * 32 + lk]);
        gl2lds16(Bt + (n0 + lr) * K + k0 + lk, &Bs[lr * 32 + lk]);
        gl2lds16(Bt + (n0 + 64 + lr) * K + k0 + lk, &Bs[(64 + lr) * 32 + lk]);
        __syncthreads();
        short8 af[2], bfr[4];
#pragma unroll
        for (int i = 0; i < 2; i++)
            af[i] = *(const short8*)&As[(wm * 32 + i * 16 + lm) * 32 + quad * 8];
#pragma unroll
        for (int j = 0; j < 4; j++)
            bfr[j] = *(const short8*)&Bs[(wn * 64 + j * 16 + lm) * 32 + quad * 8];
#pragma unroll
        for (int i = 0; i < 2; i++)
#pragma unroll
            for (int j = 0; j < 4; j++)
                acc[i][j] = __builtin_amdgcn_mfma_f32_16x16x32_bf16(af[i], bfr[j], acc[i][j], 0, 0, 0);
    }
#pragma unroll
    for (int i = 0; i < 2; i++) {
#pragma unroll
        for (int j = 0; j < 4; j++) {
            int n = (int)n0 + wn * 64 + j * 16 + lm;
            float bv = bias[n];
#pragma unroll
            for (int r = 0; r < 4; r++) {
                int m = (int)m0 + wm * 32 + i * 16 + quad * 4 + r;
                float v = acc[i][j][r] + bv;
                if (relu) v = fmaxf(v, 0.f);
                if (Cf) Cf[(long)m * N + n] = v;
                if (Cb) Cb[(long)m * N + n] = f2bf(v);
            }
        }
    }
}

// ---------------------------------------------------------------- bf16 MFMA GEMM, 64x64 tile (async LDS)
__global__ __launch_bounds__(256) void gemm_mfma_bt6464_kernel(
    const ushort* __restrict__ A, const ushort* __restrict__ Bt,
    const float* __restrict__ bias, float* __restrict__ Cf, ushort* __restrict__ Cb,
    int M, int N, int K, int relu)
{
    __shared__ ushort As[64 * 32];
    __shared__ ushort Bs[64 * 32];
    int t = threadIdx.x;
    int w = t >> 6, l = t & 63;
    int quad = l >> 4, lm = l & 15;
    int wm = w >> 1, wn = w & 1;
    long m0 = blockIdx.y * 64L;
    long n0 = blockIdx.x * 64L;
    int lr = t >> 2;
    int lk = (t & 3) * 8;
    f32x4 acc[2][2];
#pragma unroll
    for (int i = 0; i < 2; i++)
#pragma unroll
        for (int j = 0; j < 2; j++) acc[i][j] = (f32x4){0.f, 0.f, 0.f, 0.f};

    for (int k0 = 0; k0 < K; k0 += 32) {
        __syncthreads();
        gl2lds16(A + (m0 + lr) * K + k0 + lk, &As[lr * 32 + lk]);
        gl2lds16(Bt + (n0 + lr) * K + k0 + lk, &Bs[lr * 32 + lk]);
        __syncthreads();
        short8 af[2], bfr[2];
#pragma unroll
        for (int i = 0; i < 2; i++)
            af[i] = *(const short8*)&As[(wm * 32 + i * 16 + lm) * 32 + quad * 8];
#pragma unroll
        for (int j = 0; j < 2; j++)
            bfr[j] = *(const short8*)&Bs[(wn * 32 + j * 16 + lm) * 32 + quad * 8];
#pragma unroll
        for (int i = 0; i < 2; i++)
#pragma unroll
            for (int j = 0; j < 2; j++)
                acc[i][j] = __builtin_amdgcn_mfma_f32_16x16x32_bf16(af[i], bfr[j], acc[i][j], 0, 0, 0);
    }
#pragma unroll
    for (int i = 0; i < 2; i++) {
#pragma unroll
        for (int j = 0; j < 2; j++) {
            int n = (int)n0 + wn * 32 + j * 16 + lm;
            float bv = bias[n];
#pragma unroll
            for (int r = 0; r < 4; r++) {
                int m = (int)m0 + wm * 32 + i * 16 + quad * 4 + r;
                float v = acc[i][j][r] + bv;
                if (relu) v = fmaxf(v, 0.f);
                if (Cf) Cf[(long)m * N + n] = v;
                if (Cb) Cb[(long)m * N + n] = f2bf(v);
            }
        }
    }
}

// ---------------------------------------------------------------- wc3 head
__global__ __launch_bounds__(256) void wc3_kernel(const float* __restrict__ h2,
                                                  const float* __restrict__ wc3t,
                                                  const float* __restrict__ bc3,
                                                  float* __restrict__ out) {
    int r8 = threadIdx.x >> 5;
    int c = threadIdx.x & 31;
    long row = blockIdx.x * 8L + r8;
    const float* hr = h2 + row * 512;
    float acc = 0.f;
    if (c < 30) {
        for (int k = 0; k < 512; k++)
            acc += hr[k] * wc3t[k * 30 + c];
        acc += bc3[c];
        if (c < 6) out[row * 6 + c] = acc;
        else       out[49152 + row * 24 + (c - 6)] = acc;
    }
}

// ---------------------------------------------------------------- fuse (row-per-block)
__global__ __launch_bounds__(256) void fuse_bf_kernel(
    const float* __restrict__ fm0, const float* __restrict__ fm1,
    const float* __restrict__ fm2, const float* __restrict__ fm3,
    const float* __restrict__ fm4, const unsigned* __restrict__ fg_enc,
    const float* __restrict__ onehot,
    const int* __restrict__ n1, const int* __restrict__ n2,
    ushort* __restrict__ fuse_b, float* __restrict__ feat) {
    long row = blockIdx.x;
    int b = (int)(row >> 11);
    int i1 = n1[row], i2 = n2[row];
    const float* p0 = fm0 + row * 128;
    const float* p1 = fm1 + row * 128;
    const float* p2 = fm2 + ((long)b * 512 + i1) * 256;
    const float* p3 = fm3 + ((long)b * 512 + i1) * 256;
    const float* p4 = fm4 + ((long)b * 128 + i2) * 512;
    const unsigned* pg = fg_enc + b * 512;
    const float* po = onehot + b * 16;
    ushort* fb = fuse_b + row * 1824;
    float* ft = feat + row * 1296;
#pragma unroll
    for (int k = 0; k < 8; k++) {
        int c = threadIdx.x + k * 256;
        if (c >= 1824) break;
        float val = 0.f;
        if (c < 128)       val = p0[c];
        else if (c < 256)  val = p1[c - 128];
        else if (c < 512)  val = p2[c - 256];
        else if (c < 768)  val = p3[c - 512];
        else if (c < 1280) val = p4[c - 768];
        else if (c < 1792) val = fdec(pg[c - 1280]);
        else if (c < 1808) val = po[c - 1792];
        fb[c] = f2bf(val);
        if (c < 1280)                   ft[c] = val;
        else if (c >= 1792 && c < 1808) ft[c - 512] = val;
    }
}

// ---------------------------------------------------------------- launch

extern "C" void kernel_launch(void* const* d_in, const int* in_sizes, int n_in,
                              void* d_out, int out_size, void* d_ws, size_t ws_size,
                              hipStream_t stream) {
    const float* verts  = (const float*)d_in[0];
    const float* onehot = (const float*)d_in[1];
    const float* dir0 = (const float*)d_in[2];
    const float* w1 = (const float*)d_in[3];
    const float* b1 = (const float*)d_in[4];
    const float* dir1 = (const float*)d_in[5];
    const float* w2 = (const float*)d_in[6];
    const float* b2 = (const float*)d_in[7];
    const float* dir2 = (const float*)d_in[8];
    const float* w3 = (const float*)d_in[9];
    const float* b3 = (const float*)d_in[10];
    const float* dir3 = (const float*)d_in[11];
    const float* w4 = (const float*)d_in[12];
    const float* b4 = (const float*)d_in[13];
    const float* dir4 = (const float*)d_in[14];
    const float* g_bn1 = (const float*)d_in[15];
    const float* be_bn1 = (const float*)d_in[16];
    const float* g_bn2 = (const float*)d_in[17];
    const float* be_bn2 = (const float*)d_in[18];
    const float* g_bn3 = (const float*)d_in[19];
    const float* be_bn3 = (const float*)d_in[20];
    const float* wc1 = (const float*)d_in[21];
    const float* bc1 = (const float*)d_in[22];
    const float* wc2 = (const float*)d_in[23];
    const float* bc2 = (const float*)d_in[24];
    const float* wc3 = (const float*)d_in[25];
    const float* bc3 = (const float*)d_in[26];
    float* outf = (float*)d_out;

    float* wsf = (float*)d_ws;
    size_t off = 0;
    auto alloc = [&](size_t n) { float* p = wsf + off; off += (n + 15) & ~(size_t)15; return p; };

    float* sd0 = alloc(3 * 896);
    float* sd1 = alloc(3 * 896);
    float* sd2 = alloc(3 * 1792);
    float* sd3 = alloc(3 * 1792);
    float* sd4 = alloc(3 * 3584);
    float* wc3t = alloc(512L * 30);
    float* fm0 = alloc(8192L * 128);
    float* fm1 = alloc(8192L * 128);
    float* c1  = alloc(8192L * 128);
    float* fm2 = alloc(2048L * 256);
    float* c2  = alloc(2048L * 256);
    float* fm3 = alloc(2048L * 256);
    float* c3  = alloc(2048L * 256);
    float* fm4 = alloc(512L * 512);
    float* statbase = alloc(3328);
    float* stat1 = statbase;
    float* stat2 = statbase + 256;
    float* stat3 = statbase + 768;
    unsigned* fg_enc = (unsigned*)(statbase + 1280);
    float* fbuf = alloc(8192L * 1024);
    float* h2 = alloc(8192L * 512);
    float* pd  = alloc(KTOT);
    ushort* pi = (ushort*)alloc(KTOT / 2);
    int* nb   = (int*)alloc(8192L * KNB);
    int* nb1  = (int*)alloc(2048L * KNB);
    int* nb2  = (int*)alloc(512L * KNB);
    int* nbp1 = (int*)alloc(2048L * 4);
    int* nbp2 = (int*)alloc(512L * 4);
    int* n1   = (int*)alloc(8192);
    int* n2   = (int*)alloc(8192);
    ushort* fuse_b = (ushort*)alloc(8192L * 1824 / 2);
    ushort* h1b    = (ushort*)alloc(8192L * 512 / 2);
    ushort* wc1b   = (ushort*)alloc(512L * 1824 / 2);
    ushort* wc2b   = (ushort*)alloc(512L * 512 / 2);
    ushort* w1tb   = (ushort*)alloc(1024L * 128 / 2);
    ushort* w2tb   = (ushort*)alloc(2048L * 128 / 2);
    ushort* w3tb   = (ushort*)alloc(2048L * 256 / 2);
    ushort* w4tb   = (ushort*)alloc(4096L * 256 / 2);
    ushort* fm0b   = (ushort*)alloc(8192L * 128 / 2);
    ushort* fp1b   = (ushort*)alloc(2048L * 128 / 2);
    ushort* fm2b   = (ushort*)alloc(2048L * 256 / 2);
    ushort* fp2b   = (ushort*)alloc(512L * 256 / 2);

    auto nblk = [](long n, int b) { return (unsigned)((n + b - 1) / b); };

    hipMemsetAsync(statbase, 0, 3328 * sizeof(float), stream);

    // fused front: knn partials + nearest + prep + weight transpose (mutually independent)
    front_uber<<<1088 + PREP_BLOCKS + 1920, 256, 0, stream>>>(
        verts, pd, pi, n1, n2,
        dir0, dir1, dir2, dir3, dir4, sd0, sd1, sd2, sd3, sd4,
        wc3, wc3t, wc1, wc1b, wc2, wc2b,
        w1, w2, w3, w4, w1tb, w2tb, w3tb, w4tb);

    knn_merge_uber<<<2184, 256, 0, stream>>>(pd, pi, nb, nb1, nb2, nbp1, nbp2);

    conv_surface_kernel<<<BSZ * 2048, 128, 0, stream>>>(verts, nb, sd0, fm0, fm0b);

    // layer1 (M=8192, N=1024, K=128)
    gemm_mfma_bt_kernel<<<dim3(8, 64), 256, 0, stream>>>(fm0b, w1tb, b1, fbuf, nullptr, 8192, 1024, 128, 0);
    conv_act_kernel<<<BSZ * 2048, 128, 0, stream>>>(verts, nb, sd1, fbuf, c1, nullptr, 2048, 128);
    bn_stat_kernel<<<256, 256, 0, stream>>>(c1, stat1, 8192, 128);
    bn_apply_relu_kernel<<<nblk(8192L * 128, 256), 256, 0, stream>>>(c1, stat1, g_bn1, be_bn1, fm1, nullptr, 8192, 128);

    pool_b_kernel<<<nblk(BSZ * 512L * 128, 256), 256, 0, stream>>>(fm1, nbp1, fp1b, 2048, 512, 128);

    // layer2 (M=2048, N=2048, K=128)
    gemm_mfma_bt64_kernel<<<dim3(16, 32), 256, 0, stream>>>(fp1b, w2tb, b2, fbuf, nullptr, 2048, 2048, 128, 0);
    conv_act_kernel<<<BSZ * 512, 256, 0, stream>>>(verts, nb1, sd2, fbuf, c2, nullptr, 512, 256);
    bn_stat_kernel<<<256, 256, 0, stream>>>(c2, stat2, 2048, 256);
    bn_apply_relu_kernel<<<nblk(2048L * 256, 256), 256, 0, stream>>>(c2, stat2, g_bn2, be_bn2, fm2, fm2b, 2048, 256);

    // layer3 (M=2048, N=2048, K=256)
    gemm_mfma_bt64_kernel<<<dim3(16, 32), 256, 0, stream>>>(fm2b, w3tb, b3, fbuf, nullptr, 2048, 2048, 256, 0);
    conv_act_kernel<<<BSZ * 512, 256, 0, stream>>>(verts, nb1, sd3, fbuf, c3, nullptr, 512, 256);
    bn_stat_kernel<<<256, 256, 0, stream>>>(c3, stat3, 2048, 256);
    bn_apply_relu_kernel<<<nblk(2048L * 256, 256), 256, 0, stream>>>(c3, stat3, g_bn3, be_bn3, fm3, nullptr, 2048, 256);

    pool_b_kernel<<<nblk(BSZ * 128L * 256, 256), 256, 0, stream>>>(fm3, nbp2, fp2b, 512, 128, 256);

    // layer4 (M=512, N=4096, K=256) -- 64x64 tile: 512 blocks (2/CU)
    gemm_mfma_bt6464_kernel<<<dim3(64, 8), 256, 0, stream>>>(fp2b, w4tb, b4, fbuf, nullptr, 512, 4096, 256, 0);
    conv_act_kernel<<<BSZ * 128, 512, 0, stream>>>(verts, nb2, sd4, fbuf, fm4, fg_enc, 128, 512);

    // fuse -> bf16 GEMM input + fp32 feat (direct to d_out)
    fuse_bf_kernel<<<8192, 256, 0, stream>>>(fm0, fm1, fm2, fm3, fm4, fg_enc, onehot,
                                             n1, n2, fuse_b, outf + 245760);

    // MLP head (M=8192, N=512) -- 64x128 tile + XCD-panel swizzle (CB=4 col-blocks share A panel per XCD)
    gemm_mfma_bt64x_kernel<<<512, 256, 0, stream>>>(fuse_b, wc1b, bc1, nullptr, h1b, 8192, 512, 1824, 1, 4);
    gemm_mfma_bt64x_kernel<<<512, 256, 0, stream>>>(h1b, wc2b, bc2, h2, nullptr, 8192, 512, 512, 1, 4);
    wc3_kernel<<<1024, 256, 0, stream>>>(h2, wc3t, bc3, outf);
}

// Round 13
// 441.734 us; speedup vs baseline: 1.0423x; 1.0014x over previous
//
#include <hip/hip_runtime.h>
#include <hip/hip_bf16.h>
#include <math.h>

#define BSZ 4
#define VN 2048
#define SS 7
#define KNB 10

typedef __attribute__((ext_vector_type(8))) short short8;
typedef __attribute__((ext_vector_type(4))) float f32x4;
typedef __attribute__((address_space(1))) const void gcvoid;
typedef __attribute__((address_space(3))) void lvoid;

__device__ inline ushort f2bf(float x) {
    __hip_bfloat16 h = __float2bfloat16(x);
    return *(ushort*)&h;
}

__device__ inline void gl2lds16(const ushort* g, ushort* l) {
    __builtin_amdgcn_global_load_lds((gcvoid*)g, (lvoid*)l, 16, 0, 0);
}

__device__ inline unsigned fenc(float f) {
    unsigned b = __float_as_uint(f);
    return (b & 0x80000000u) ? ~b : (b | 0x80000000u);
}
__device__ inline float fdec(unsigned e) {
    unsigned b = (e & 0x80000000u) ? (e & 0x7FFFFFFFu) : ~e;
    return __uint_as_float(b);
}

#define INS(dq, iq, dd, jj) { bool lt_ = (dd) < (dq); \
    float dmn_ = lt_ ? (dd) : (dq); float dmx_ = lt_ ? (dq) : (dd); \
    int imn_ = lt_ ? (jj) : (iq); int imx_ = lt_ ? (iq) : (jj); \
    (dq) = dmn_; (iq) = imn_; (dd) = dmx_; (jj) = imx_; }

// ---------------------------------------------------------------- prep (device fn; part of front_uber)
#define PB0 8960L
#define PB1 24320L
#define PB2 958208L
#define PB3 1220352L
#define PREP_BLOCKS 4767        // PB3 / 256

__device__ void prep_dev(int gb,
                         const float* __restrict__ d0, const float* __restrict__ d1,
                         const float* __restrict__ d2, const float* __restrict__ d3,
                         const float* __restrict__ d4,
                         float* __restrict__ s0, float* __restrict__ s1,
                         float* __restrict__ s2, float* __restrict__ s3, float* __restrict__ s4,
                         const float* __restrict__ wc3, float* __restrict__ wc3t,
                         const float* __restrict__ wc1, ushort* __restrict__ wc1b,
                         const float* __restrict__ wc2, ushort* __restrict__ wc2b) {
    long i = gb * 256L + threadIdx.x;
    if (i < PB0) {
        const float* src; float* dst; int C, c;
        if (i < 896)        { src = d0; dst = s0; C = 896;  c = (int)i; }
        else if (i < 1792)  { src = d1; dst = s1; C = 896;  c = (int)i - 896; }
        else if (i < 3584)  { src = d2; dst = s2; C = 1792; c = (int)i - 1792; }
        else if (i < 5376)  { src = d3; dst = s3; C = 1792; c = (int)i - 3584; }
        else                { src = d4; dst = s4; C = 3584; c = (int)i - 5376; }
        float a = src[c], b = src[C + c], e = src[2 * C + c];
        float den = fmaxf(sqrtf(a * a + b * b + e * e), 1e-12f);
        dst[c] = a / den; dst[C + c] = b / den; dst[2 * C + c] = e / den;
    } else if (i < PB1) {
        long j = i - PB0;
        int o = (int)(j / 512), k = (int)(j % 512);
        wc3t[(long)k * 30 + o] = wc3[j];
    } else if (i < PB2) {
        long j = i - PB1;
        int c = (int)(j % 1824);
        long r = j / 1824;
        wc1b[j] = f2bf(c < 1808 ? wc1[r * 1808 + c] : 0.f);
    } else if (i < PB3) {
        long j = i - PB2;
        wc2b[j] = f2bf(wc2[j]);
    }
}

// ---------------------------------------------------------------- weight transpose (device fn; part of front_uber)
__device__ void wt_trans_dev(int gb, float* tilef,
                             const float* __restrict__ w1, const float* __restrict__ w2,
                             const float* __restrict__ w3, const float* __restrict__ w4,
                             ushort* __restrict__ o1, ushort* __restrict__ o2,
                             ushort* __restrict__ o3, ushort* __restrict__ o4) {
    const float* w; ushort* o; int K, N, t;
    if (gb < 128)      { w = w1; o = o1; K = 128; N = 1024; t = gb; }
    else if (gb < 384) { w = w2; o = o2; K = 128; N = 2048; t = gb - 128; }
    else if (gb < 896) { w = w3; o = o3; K = 256; N = 2048; t = gb - 384; }
    else               { w = w4; o = o4; K = 256; N = 4096; t = gb - 896; }
    int tn = t % (N / 32), tk = t / (N / 32);
    int n0 = tn * 32, k0 = tk * 32;
    int tx = threadIdx.x % 32, ty = threadIdx.x / 32;
#pragma unroll
    for (int r = 0; r < 32; r += 8)
        tilef[(ty + r) * 33 + tx] = w[(long)(k0 + ty + r) * N + n0 + tx];
    __syncthreads();
#pragma unroll
    for (int r = 0; r < 32; r += 8)
        o[(long)(n0 + ty + r) * K + k0 + tx] = f2bf(tilef[tx * 33 + ty + r]);
}

// ---------------------------------------------------------------- knn part (exact fp32, 64-source chunks)
// Only the 2048x2048 pass is computed: pooled point sets vp1/vp2 are PREFIXES of vertices
// (verts[:, :512], verts[:, :128]), so their partial lists are sub-slices of the big run.
// per target, per 64-source chunk: 2 sorted 10-lists (sublists of 32 sources, ascending index ranges)
// pd[ ((b*2048 + i)*32 + ch)*20 + l*10 + q ] == row (b*2048+i), list c=2*ch+l at (row*64+c)*10
#define KTOT  5242880L

__device__ void knn_part_dev(const float* __restrict__ verts, int T, int nch,
                             int tile, int b, int ch,
                             float* __restrict__ pd, ushort* __restrict__ pi,
                             float4* __restrict__ s4) {
    const float* vb = verts + (long)b * VN * 3;
    int j0 = ch * 64;
    for (int j = threadIdx.x; j < 64; j += 256) {
        float x = vb[(j0 + j) * 3 + 0];
        float y = vb[(j0 + j) * 3 + 1];
        float z = vb[(j0 + j) * 3 + 2];
        s4[j] = make_float4(x, y, z, x * x + y * y + z * z);
    }
    __syncthreads();
    int i = tile * 256 + (int)threadIdx.x;
    if (i >= T) return;
    float px = vb[i * 3], py = vb[i * 3 + 1], pz = vb[i * 3 + 2];
    float d0[10], d1[10];
    int id0[10], id1[10];
#pragma unroll
    for (int q = 0; q < 10; q++) {
        d0[q] = 1e30f; d1[q] = 1e30f;
        id0[q] = 0; id1[q] = 0;
    }
    for (int j = 0; j < 32; j++) {
        float4 sA = s4[j];
        float4 sB = s4[32 + j];
        float dA = fmaf(-2.f, px * sA.x + py * sA.y + pz * sA.z, sA.w);
        float dB = fmaf(-2.f, px * sB.x + py * sB.y + pz * sB.z, sB.w);
        int jA = j0 + j, jB = j0 + 32 + j;
        dA = (jA == i) ? 1e30f : dA;
        dB = (jB == i) ? 1e30f : dB;
#pragma unroll
        for (int q = 0; q < 10; q++) { INS(d0[q], id0[q], dA, jA); }
#pragma unroll
        for (int q = 0; q < 10; q++) { INS(d1[q], id1[q], dB, jB); }
    }
    long base = ((long)(b * T + i) * nch + ch) * 20;
    // vectorized stores: base is a multiple of 20 floats (80B) -> list0 16B-aligned, list1 (+40B) 8B-aligned
    *(float4*)(pd + base)      = make_float4(d0[0], d0[1], d0[2], d0[3]);
    *(float4*)(pd + base + 4)  = make_float4(d0[4], d0[5], d0[6], d0[7]);
    *(float2*)(pd + base + 8)  = make_float2(d0[8], d0[9]);
    *(float2*)(pd + base + 10) = make_float2(d1[0], d1[1]);
    *(float2*)(pd + base + 12) = make_float2(d1[2], d1[3]);
    *(float2*)(pd + base + 14) = make_float2(d1[4], d1[5]);
    *(float2*)(pd + base + 16) = make_float2(d1[6], d1[7]);
    *(float2*)(pd + base + 18) = make_float2(d1[8], d1[9]);
    // index pairs packed little-endian u16|u16<<16 == the u32 words the merge reads
    uint* pu = (uint*)(pi + base);
#pragma unroll
    for (int q = 0; q < 5; q++)
        pu[q] = (uint)(ushort)id0[2 * q] | ((uint)(ushort)id0[2 * q + 1] << 16);
#pragma unroll
    for (int q = 0; q < 5; q++)
        pu[5 + q] = (uint)(ushort)id1[2 * q] | ((uint)(ushort)id1[2 * q + 1] << 16);
}

__device__ void nearest_dev(const float* __restrict__ verts, int SN, int* __restrict__ out,
                            int gl, float4* __restrict__ s4) {
    int t = gl * 256 + (int)threadIdx.x;
    int b = t / VN;
    const float* vb = verts + (long)b * VN * 3;
    for (int j = threadIdx.x; j < SN; j += 256) {
        float x = vb[j * 3], y = vb[j * 3 + 1], z = vb[j * 3 + 2];
        s4[j] = make_float4(x, y, z, x * x + y * y + z * z);
    }
    __syncthreads();
    int i = t % VN;
    float px = vb[i * 3], py = vb[i * 3 + 1], pz = vb[i * 3 + 2];
    int h = SN / 2;
    float b0 = 1e30f, b1 = 1e30f; int i0 = 0, i1 = 0;
    for (int j = 0; j < h; j++) {
        float4 sA = s4[j];
        float4 sB = s4[h + j];
        float dA = fmaf(-2.f, px * sA.x + py * sA.y + pz * sA.z, sA.w);
        float dB = fmaf(-2.f, px * sB.x + py * sB.y + pz * sB.z, sB.w);
        bool lA = dA < b0; b0 = lA ? dA : b0; i0 = lA ? j : i0;
        bool lB = dB < b1; b1 = lB ? dB : b1; i1 = lB ? (h + j) : i1;
    }
    out[t] = (b1 < b0) ? i1 : i0;
}

// ---------------------------------------------------------------- front uber: knn part + nearest + prep + weight transpose
//  [0,1024)        knn big: 8 tiles x (4 b x 32 ch)   2048x2048
//  [1024,1056)     nearest n1 (512 sources)
//  [1056,1088)     nearest n2 (128 sources)
//  [1088,5855)     prep (4767 blocks)
//  [5855,7775)     weight transpose (1920 blocks)
__global__ __launch_bounds__(256) void front_uber(const float* __restrict__ verts,
                                                  float* __restrict__ pd, ushort* __restrict__ pi,
                                                  int* __restrict__ n1, int* __restrict__ n2,
                                                  const float* __restrict__ d0, const float* __restrict__ d1,
                                                  const float* __restrict__ d2, const float* __restrict__ d3,
                                                  const float* __restrict__ d4,
                                                  float* __restrict__ s0, float* __restrict__ s1,
                                                  float* __restrict__ s2, float* __restrict__ s3,
                                                  float* __restrict__ s4v,
                                                  const float* __restrict__ wc3, float* __restrict__ wc3t,
                                                  const float* __restrict__ wc1, ushort* __restrict__ wc1b,
                                                  const float* __restrict__ wc2, ushort* __restrict__ wc2b,
                                                  const float* __restrict__ w1, const float* __restrict__ w2,
                                                  const float* __restrict__ w3, const float* __restrict__ w4,
                                                  ushort* __restrict__ o1, ushort* __restrict__ o2,
                                                  ushort* __restrict__ o3, ushort* __restrict__ o4) {
    __shared__ float4 smem[512];        // knn/nearest: float4[512]; trans: float[32][33] alias
    int gb = blockIdx.x;
    if (gb < 1024) {
        int tile = gb & 7, bc = gb >> 3;
        knn_part_dev(verts, 2048, 32, tile, bc >> 5, bc & 31, pd, pi, smem);
    } else if (gb < 1056) {
        nearest_dev(verts, 512, n1, gb - 1024, smem);
    } else if (gb < 1088) {
        nearest_dev(verts, 128, n2, gb - 1056, smem);
    } else if (gb < 1088 + PREP_BLOCKS) {
        prep_dev(gb - 1088, d0, d1, d2, d3, d4, s0, s1, s2, s3, s4v,
                 wc3, wc3t, wc1, wc1b, wc2, wc2b);
    } else {
        wt_trans_dev(gb - (1088 + PREP_BLOCKS), (float*)smem, w1, w2, w3, w4, o1, o2, o3, o4);
    }
}

// ---------------------------------------------------------------- knn selection: lane-per-list tournament
template <int G>
__device__ void knn_sel_dev(const float* __restrict__ pd, const ushort* __restrict__ pi,
                            int blk, int Tsub, int* __restrict__ out,
                            int* __restrict__ outp, int Tp) {
    typedef unsigned long long u64;
    constexpr int TPB = 256 / G;        // targets per block
    int tid = threadIdx.x;
    long t = (long)blk * TPB + (tid / G);
    int c = tid % G;
    int bb = (int)(t / Tsub), ii = (int)(t % Tsub);
    long row = (long)bb * 2048 + ii;
    long base = (row * 64 + c) * 10;
    const float2* pf = (const float2*)(pd + base);   // 40B stride -> 8B aligned
    const uint*   pu = (const uint*)(pi + base);     // 20B stride -> 4B aligned
    float2 f0 = pf[0], f1 = pf[1], f2 = pf[2], f3 = pf[3], f4 = pf[4];
    uint   u0 = pu[0], u1 = pu[1], u2 = pu[2], u3 = pu[3], u4 = pu[4];
    u64 k0 = ((u64)fenc(f0.x) << 32) | (u0 & 0xFFFFu);
    u64 k1 = ((u64)fenc(f0.y) << 32) | (u0 >> 16);
    u64 k2 = ((u64)fenc(f1.x) << 32) | (u1 & 0xFFFFu);
    u64 k3 = ((u64)fenc(f1.y) << 32) | (u1 >> 16);
    u64 k4 = ((u64)fenc(f2.x) << 32) | (u2 & 0xFFFFu);
    u64 k5 = ((u64)fenc(f2.y) << 32) | (u2 >> 16);
    u64 k6 = ((u64)fenc(f3.x) << 32) | (u3 & 0xFFFFu);
    u64 k7 = ((u64)fenc(f3.y) << 32) | (u3 >> 16);
    u64 k8 = ((u64)fenc(f4.x) << 32) | (u4 & 0xFFFFu);
    u64 k9 = ((u64)fenc(f4.y) << 32) | (u4 >> 16);
    bool wp = (outp != nullptr) && (ii < Tp);
#pragma unroll
    for (int q = 0; q < 10; q++) {
        u64 m = k0;
#pragma unroll
        for (int s = 1; s < G; s <<= 1) {
            u64 o = (u64)__shfl_xor((long long)m, s);
            m = (o < m) ? o : m;
        }
        if (c == 0) {
            int idx = (int)(unsigned)(m & 0xFFFFFFFFull);
            out[t * 10 + q] = idx;
            if (wp && q < 4) outp[((long)bb * Tp + ii) * 4 + q] = idx;
        }
        if (k0 == m) {
            k0 = k1; k1 = k2; k2 = k3; k3 = k4; k4 = k5;
            k5 = k6; k6 = k7; k7 = k8; k8 = k9;
            k9 = 0xFFFFFFFFFFFFFFFFull;
        }
    }
}

// grid: [0,2048) big (8192 t, 64 lists, 4 t/blk) | [2048,2176) mid (2048 t, 16 lists, 16 t/blk)
//       | [2176,2184) small (512 t, 4 lists, 64 t/blk)
__global__ __launch_bounds__(256) void knn_merge_uber(const float* __restrict__ pd, const ushort* __restrict__ pi,
                                                      int* __restrict__ nb, int* __restrict__ nb1,
                                                      int* __restrict__ nb2, int* __restrict__ nbp1,
                                                      int* __restrict__ nbp2) {
    int gb = blockIdx.x;
    if (gb < 2048)      knn_sel_dev<64>(pd, pi, gb, 2048, nb, nbp1, 512);
    else if (gb < 2176) knn_sel_dev<16>(pd, pi, gb - 2048, 512, nb1, nbp2, 128);
    else                knn_sel_dev<4>(pd, pi, gb - 2176, 128, nb2, nullptr, 1);
}

// ---------------------------------------------------------------- conv_surface (fp32 + bf16 out)
__global__ void conv_surface_kernel(const float* __restrict__ verts, const int* __restrict__ nb,
                                    const float* __restrict__ sd, float* __restrict__ fm0,
                                    ushort* __restrict__ fm0b) {
    int bv = blockIdx.x;
    int b = bv / VN, v = bv % VN;
    __shared__ float snd[KNB][3];
    int tid = threadIdx.x;
    if (tid < KNB) {
        int nj = nb[(long)bv * KNB + tid];
        const float* vb = verts + (long)b * VN * 3;
        float dx = vb[nj * 3] - vb[v * 3];
        float dy = vb[nj * 3 + 1] - vb[v * 3 + 1];
        float dz = vb[nj * 3 + 2] - vb[v * 3 + 2];
        float den = fmaxf(sqrtf(dx * dx + dy * dy + dz * dz), 1e-12f);
        snd[tid][0] = dx / den; snd[tid][1] = dy / den; snd[tid][2] = dz / den;
    }
    __syncthreads();
    int c = tid;
    float acc = 0.f;
#pragma unroll
    for (int s = 0; s < SS; s++) {
        int col = s * 128 + c;
        float s0 = sd[col], s1 = sd[896 + col], s2 = sd[2 * 896 + col];
        float m = 0.f;
#pragma unroll
        for (int n = 0; n < KNB; n++) {
            float dot = snd[n][0] * s0 + snd[n][1] * s1 + snd[n][2] * s2;
            m = fmaxf(m, dot);
        }
        acc += m;
    }
    fm0[(long)bv * 128 + c] = acc;
    fm0b[(long)bv * 128 + c] = f2bf(acc);
}

// ---------------------------------------------------------------- conv_layer act (+opt fg max)
// s-loop fully unrolled: all 70 (s,n) gather loads are independent -> issue together for latency hiding
__global__ void conv_act_kernel(const float* __restrict__ verts, const int* __restrict__ nb,
                                const float* __restrict__ sd, const float* __restrict__ fo,
                                float* __restrict__ out, unsigned* __restrict__ fgmax,
                                int Vl, int outC) {
    int bv = blockIdx.x;
    int b = bv / Vl, v = bv % Vl;
    __shared__ float snd[KNB][3];
    __shared__ int srow[KNB];
    int tid = threadIdx.x;
    if (tid < KNB) {
        int nj = nb[(long)bv * KNB + tid];
        srow[tid] = b * Vl + nj;
        const float* vb = verts + (long)b * VN * 3;
        float dx = vb[nj * 3] - vb[v * 3];
        float dy = vb[nj * 3 + 1] - vb[v * 3 + 1];
        float dz = vb[nj * 3 + 2] - vb[v * 3 + 2];
        float den = fmaxf(sqrtf(dx * dx + dy * dy + dz * dz), 1e-12f);
        snd[tid][0] = dx / den; snd[tid][1] = dy / den; snd[tid][2] = dz / den;
    }
    __syncthreads();
    int c = tid;
    int SC = SS * outC;
    int foN = SC + outC;
    float acc = fo[(long)bv * foN + c];
#pragma unroll
    for (int s = 0; s < SS; s++) {
        int col = s * outC + c;
        float s0 = sd[col], s1 = sd[SC + col], s2 = sd[2 * SC + col];
        float m = -1e30f;
#pragma unroll
        for (int n = 0; n < KNB; n++) {
            float dot = snd[n][0] * s0 + snd[n][1] * s1 + snd[n][2] * s2;
            float th = fmaxf(dot, 0.f);
            float sup = fo[(long)srow[n] * foN + outC + col];
            m = fmaxf(m, th * sup);
        }
        acc += m;
    }
    out[(long)bv * outC + c] = acc;
    if (fgmax) atomicMax(&fgmax[b * outC + c], fenc(acc));
}

// ---------------------------------------------------------------- batchnorm stats
__global__ __launch_bounds__(256) void bn_stat_kernel(const float* __restrict__ x,
                                                      float* __restrict__ stat, int R, int C) {
    int rp = 256 / C;
    int c = threadIdx.x % C;
    int rs = threadIdx.x / C;
    float s = 0.f, s2 = 0.f;
    for (long r = (long)blockIdx.x * rp + rs; r < R; r += (long)gridDim.x * rp) {
        float v = x[r * C + c];
        s += v; s2 += v * v;
    }
    atomicAdd(&stat[c], s);
    atomicAdd(&stat[C + c], s2);
}

__global__ void bn_apply_relu_kernel(const float* __restrict__ x, const float* __restrict__ stat,
                                     const float* __restrict__ g, const float* __restrict__ be,
                                     float* __restrict__ out, ushort* __restrict__ outb, int R, int C) {
    long i = blockIdx.x * 256L + threadIdx.x;
    if (i >= (long)R * C) return;
    int c = (int)(i % C);
    float mu = stat[c] / R;
    float var = stat[C + c] / R - mu * mu;
    var = fmaxf(var, 0.f);
    float y = (x[i] - mu) * rsqrtf(var + 1e-5f) * g[c] + be[c];
    y = fmaxf(y, 0.f);
    out[i] = y;
    if (outb) outb[i] = f2bf(y);
}

// ---------------------------------------------------------------- pool -> bf16
__global__ void pool_b_kernel(const float* __restrict__ fm, const int* __restrict__ idx,
                              ushort* __restrict__ out, int Vin, int T, int C) {
    long i = blockIdx.x * 256L + threadIdx.x;
    if (i >= (long)BSZ * T * C) return;
    int c = (int)(i % C);
    long bt = i / C;
    int b = (int)(bt / T), t = (int)(bt % T);
    const int* id = idx + ((long)b * T + t) * 4;
    float m = -1e30f;
#pragma unroll
    for (int n = 0; n < 4; n++)
        m = fmaxf(m, fm[((long)b * Vin + id[n]) * C + c]);
    out[i] = f2bf(m);
}

// ---------------------------------------------------------------- bf16 MFMA GEMM, 128x128 tile (async LDS)
__global__ __launch_bounds__(256) void gemm_mfma_bt_kernel(
    const ushort* __restrict__ A, const ushort* __restrict__ Bt,
    const float* __restrict__ bias, float* __restrict__ Cf, ushort* __restrict__ Cb,
    int M, int N, int K, int relu)
{
    __shared__ ushort As[128 * 32];
    __shared__ ushort Bs[128 * 32];
    int t = threadIdx.x;
    int w = t >> 6, l = t & 63;
    int quad = l >> 4, lm = l & 15;
    int wm = w >> 1, wn = w & 1;
    long m0 = blockIdx.y * 128L;
    long n0 = blockIdx.x * 128L;
    int lr = t >> 2;
    int lk = (t & 3) * 8;
    f32x4 acc[4][4];
#pragma unroll
    for (int i = 0; i < 4; i++)
#pragma unroll
        for (int j = 0; j < 4; j++) acc[i][j] = (f32x4){0.f, 0.f, 0.f, 0.f};

    for (int k0 = 0; k0 < K; k0 += 32) {
        __syncthreads();
        gl2lds16(A + (m0 + lr) * K + k0 + lk, &As[lr * 32 + lk]);
        gl2lds16(A + (m0 + 64 + lr) * K + k0 + lk, &As[(64 + lr) * 32 + lk]);
        gl2lds16(Bt + (n0 + lr) * K + k0 + lk, &Bs[lr * 32 + lk]);
        gl2lds16(Bt + (n0 + 64 + lr) * K + k0 + lk, &Bs[(64 + lr) * 32 + lk]);
        __syncthreads();
        short8 af[4], bfr[4];
#pragma unroll
        for (int i = 0; i < 4; i++)
            af[i] = *(const short8*)&As[(wm * 64 + i * 16 + lm) * 32 + quad * 8];
#pragma unroll
        for (int j = 0; j < 4; j++)
            bfr[j] = *(const short8*)&Bs[(wn * 64 + j * 16 + lm) * 32 + quad * 8];
#pragma unroll
        for (int i = 0; i < 4; i++)
#pragma unroll
            for (int j = 0; j < 4; j++)
                acc[i][j] = __builtin_amdgcn_mfma_f32_16x16x32_bf16(af[i], bfr[j], acc[i][j], 0, 0, 0);
    }
#pragma unroll
    for (int i = 0; i < 4; i++) {
#pragma unroll
        for (int j = 0; j < 4; j++) {
            int n = (int)n0 + wn * 64 + j * 16 + lm;
            float bv = bias[n];
#pragma unroll
            for (int r = 0; r < 4; r++) {
                int m = (int)m0 + wm * 64 + i * 16 + quad * 4 + r;
                float v = acc[i][j][r] + bv;
                if (relu) v = fmaxf(v, 0.f);
                if (Cf) Cf[(long)m * N + n] = v;
                if (Cb) Cb[(long)m * N + n] = f2bf(v);
            }
        }
    }
}

// ---------------------------------------------------------------- bf16 MFMA GEMM, 64x128 tile (async LDS)
__global__ __launch_bounds__(256) void gemm_mfma_bt64_kernel(
    const ushort* __restrict__ A, const ushort* __restrict__ Bt,
    const float* __restrict__ bias, float* __restrict__ Cf, ushort* __restrict__ Cb,
    int M, int N, int K, int relu)
{
    __shared__ ushort As[64 * 32];
    __shared__ ushort Bs[128 * 32];
    int t = threadIdx.x;
    int w = t >> 6, l = t & 63;
    int quad = l >> 4, lm = l & 15;
    int wm = w >> 1, wn = w & 1;
    long m0 = blockIdx.y * 64L;
    long n0 = blockIdx.x * 128L;
    int lr = t >> 2;
    int lk = (t & 3) * 8;
    f32x4 acc[2][4];
#pragma unroll
    for (int i = 0; i < 2; i++)
#pragma unroll
        for (int j = 0; j < 4; j++) acc[i][j] = (f32x4){0.f, 0.f, 0.f, 0.f};

    for (int k0 = 0; k0 < K; k0 += 32) {
        __syncthreads();
        gl2lds16(A + (m0 + lr) * K + k0 + lk, &As[lr * 32 + lk]);
        gl2lds16(Bt + (n0 + lr) * K + k0 + lk, &Bs[lr * 32 + lk]);
        gl2lds16(Bt + (n0 + 64 + lr) * K + k0 + lk, &Bs[(64 + lr) * 32 + lk]);
        __syncthreads();
        short8 af[2], bfr[4];
#pragma unroll
        for (int i = 0; i < 2; i++)
            af[i] = *(const short8*)&As[(wm * 32 + i * 16 + lm) * 32 + quad * 8];
#pragma unroll
        for (int j = 0; j < 4; j++)
            bfr[j] = *(const short8*)&Bs[(wn * 64 + j * 16 + lm) * 32 + quad * 8];
#pragma unroll
        for (int i = 0; i < 2; i++)
#pragma unroll
            for (int j = 0; j < 4; j++)
                acc[i][j] = __builtin_amdgcn_mfma_f32_16x16x32_bf16(af[i], bfr[j], acc[i][j], 0, 0, 0);
    }
#pragma unroll
    for (int i = 0; i < 2; i++) {
#pragma unroll
        for (int j = 0; j < 4; j++) {
            int n = (int)n0 + wn * 64 + j * 16 + lm;
            float bv = bias[n];
#pragma unroll
            for (int r = 0; r < 4; r++) {
                int m = (int)m0 + wm * 32 + i * 16 + quad * 4 + r;
                float v = acc[i][j][r] + bv;
                if (relu) v = fmaxf(v, 0.f);
                if (Cf) Cf[(long)m * N + n] = v;
                if (Cb) Cb[(long)m * N + n] = f2bf(v);
            }
        }
    }
}

// ---------------------------------------------------------------- bf16 MFMA GEMM, 64x128 tile, XCD-panel swizzle
// 1D grid; CB = column-blocks per A row-panel (N/128). All CB col-blocks of a row-panel are mapped to
// the SAME XCD (xcd = L%8 round-robin assumption, T1/HK chiplet pattern) so the A panel is fetched into
// that XCD's L2 once and reused CB times. Requires gridDim.x % (8*CB) == 0.
__global__ __launch_bounds__(256) void gemm_mfma_bt64x_kernel(
    const ushort* __restrict__ A, const ushort* __restrict__ Bt,
    const float* __restrict__ bias, float* __restrict__ Cf, ushort* __restrict__ Cb,
    int M, int N, int K, int relu, int CB)
{
    __shared__ ushort As[64 * 32];
    __shared__ ushort Bs[128 * 32];
    int L = blockIdx.x;
    int xcd = L & 7;
    int slot = L >> 3;
    int ppx = (int)gridDim.x / (8 * CB);    // panels per XCD
    int panel = xcd * ppx + slot / CB;
    int col = slot % CB;
    int t = threadIdx.x;
    int w = t >> 6, l = t & 63;
    int quad = l >> 4, lm = l & 15;
    int wm = w >> 1, wn = w & 1;
    long m0 = panel * 64L;
    long n0 = col * 128L;
    int lr = t >> 2;
    int lk = (t & 3) * 8;
    f32x4 acc[2][4];
#pragma unroll
    for (int i = 0; i < 2; i++)
#pragma unroll
        for (int j = 0; j < 4; j++) acc[i][j] = (f32x4){0.f, 0.f, 0.f, 0.f};

    for (int k0 = 0; k0 < K; k0 += 32) {
        __syncthreads();
        gl2lds16(A + (m0 + lr) * K + k0 + lk, &As[lr * 32 + lk]);
        gl2lds16(Bt + (n0 + lr) * K + k0 + lk, &Bs[lr * 32 + lk]);
        gl2lds16(Bt + (n0 + 64 + lr) * K + k0 + lk, &Bs[(64 + lr) * 32 + lk]);
        __syncthreads();
        short8 af[2], bfr[4];
#pragma unroll
        for (int i = 0; i < 2; i++)
            af[i] = *(const short8*)&As[(wm * 32 + i * 16 + lm) * 32 + quad * 8];
#pragma unroll
        for (int j = 0; j < 4; j++)
            bfr[j] = *(const short8*)&Bs[(wn * 64 + j * 16 + lm) * 32 + quad * 8];
#pragma unroll
        for (int i = 0; i < 2; i++)
#pragma unroll
            for (int j = 0; j < 4; j++)
                acc[i][j] = __builtin_amdgcn_mfma_f32_16x16x32_bf16(af[i], bfr[j], acc[i][j], 0, 0, 0);
    }
#pragma unroll
    for (int i = 0; i < 2; i++) {
#pragma unroll
        for (int j = 0; j < 4; j++) {
            int n = (int)n0 + wn * 64 + j * 16 + lm;
            float bv = bias[n];
#pragma unroll
            for (int r = 0; r < 4; r++) {
                int m = (int)m0 + wm * 32 + i * 16 + quad * 4 + r;
                float v = acc[i][j][r] + bv;
                if (relu) v = fmaxf(v, 0.f);
                if (Cf) Cf[(long)m * N + n] = v;
                if (Cb) Cb[(long)m * N + n] = f2bf(v);
            }
        }
    }
}

// ---------------------------------------------------------------- bf16 MFMA GEMM, 64x64 tile (async LDS)
__global__ __launch_bounds__(256) void gemm_mfma_bt6464_kernel(
    const ushort* __restrict__ A, const ushort* __restrict__ Bt,
    const float* __restrict__ bias, float* __restrict__ Cf, ushort* __restrict__ Cb,
    int M, int N, int K, int relu)
{
    __shared__ ushort As[64 * 32];
    __shared__ ushort Bs[64 * 32];
    int t = threadIdx.x;
    int w = t >> 6, l = t & 63;
    int quad = l >> 4, lm = l & 15;
    int wm = w >> 1, wn = w & 1;
    long m0 = blockIdx.y * 64L;
    long n0 = blockIdx.x * 64L;
    int lr = t >> 2;
    int lk = (t & 3) * 8;
    f32x4 acc[2][2];
#pragma unroll
    for (int i = 0; i < 2; i++)
#pragma unroll
        for (int j = 0; j < 2; j++) acc[i][j] = (f32x4){0.f, 0.f, 0.f, 0.f};

    for (int k0 = 0; k0 < K; k0 += 32) {
        __syncthreads();
        gl2lds16(A + (m0 + lr) * K + k0 + lk, &As[lr * 32 + lk]);
        gl2lds16(Bt + (n0 + lr) * K + k0 + lk, &Bs[lr * 32 + lk]);
        __syncthreads();
        short8 af[2], bfr[2];
#pragma unroll
        for (int i = 0; i < 2; i++)
            af[i] = *(const short8*)&As[(wm * 32 + i * 16 + lm) * 32 + quad * 8];
#pragma unroll
        for (int j = 0; j < 2; j++)
            bfr[j] = *(const short8*)&Bs[(wn * 32 + j * 16 + lm) * 32 + quad * 8];
#pragma unroll
        for (int i = 0; i < 2; i++)
#pragma unroll
            for (int j = 0; j < 2; j++)
                acc[i][j] = __builtin_amdgcn_mfma_f32_16x16x32_bf16(af[i], bfr[j], acc[i][j], 0, 0, 0);
    }
#pragma unroll
    for (int i = 0; i < 2; i++) {
#pragma unroll
        for (int j = 0; j < 2; j++) {
            int n = (int)n0 + wn * 32 + j * 16 + lm;
            float bv = bias[n];
#pragma unroll
            for (int r = 0; r < 4; r++) {
                int m = (int)m0 + wm * 32 + i * 16 + quad * 4 + r;
                float v = acc[i][j][r] + bv;
                if (relu) v = fmaxf(v, 0.f);
                if (Cf) Cf[(long)m * N + n] = v;
                if (Cb) Cb[(long)m * N + n] = f2bf(v);
            }
        }
    }
}

// ---------------------------------------------------------------- wc3 head (4 independent accumulators)
__global__ __launch_bounds__(256) void wc3_kernel(const float* __restrict__ h2,
                                                  const float* __restrict__ wc3t,
                                                  const float* __restrict__ bc3,
                                                  float* __restrict__ out) {
    int r8 = threadIdx.x >> 5;
    int c = threadIdx.x & 31;
    long row = blockIdx.x * 8L + r8;
    const float* hr = h2 + row * 512;
    if (c < 30) {
        float a0 = 0.f, a1 = 0.f, a2 = 0.f, a3 = 0.f;
#pragma unroll 4
        for (int k = 0; k < 512; k += 4) {
            a0 = fmaf(hr[k],     wc3t[(k)     * 30 + c], a0);
            a1 = fmaf(hr[k + 1], wc3t[(k + 1) * 30 + c], a1);
            a2 = fmaf(hr[k + 2], wc3t[(k + 2) * 30 + c], a2);
            a3 = fmaf(hr[k + 3], wc3t[(k + 3) * 30 + c], a3);
        }
        float acc = ((a0 + a1) + (a2 + a3)) + bc3[c];
        if (c < 6) out[row * 6 + c] = acc;
        else       out[49152 + row * 24 + (c - 6)] = acc;
    }
}

// ---------------------------------------------------------------- fuse (row-per-block, 2 channels/thread)
// All segment boundaries (128/256/512/768/1280/1792/1808) are even -> a (2t,2t+1) pair never straddles.
__global__ __launch_bounds__(256) void fuse_bf_kernel(
    const float* __restrict__ fm0, const float* __restrict__ fm1,
    const float* __restrict__ fm2, const float* __restrict__ fm3,
    const float* __restrict__ fm4, const unsigned* __restrict__ fg_enc,
    const float* __restrict__ onehot,
    const int* __restrict__ n1, const int* __restrict__ n2,
    ushort* __restrict__ fuse_b, float* __restrict__ feat) {
    long row = blockIdx.x;
    int b = (int)(row >> 11);
    int i1 = n1[row], i2 = n2[row];
    const float* p0 = fm0 + row * 128;
    const float* p1 = fm1 + row * 128;
    const float* p2 = fm2 + ((long)b * 512 + i1) * 256;
    const float* p3 = fm3 + ((long)b * 512 + i1) * 256;
    const float* p4 = fm4 + ((long)b * 128 + i2) * 512;
    const unsigned* pg = fg_enc + b * 512;
    const float* po = onehot + b * 16;
    ushort* fb = fuse_b + row * 1824;
    float* ft = feat + row * 1296;
#pragma unroll
    for (int k = 0; k < 4; k++) {
        int c = (threadIdx.x + k * 256) * 2;
        if (c >= 1824) break;
        float v0 = 0.f, v1 = 0.f;
        if (c < 128)       { float2 u = *(const float2*)&p0[c];        v0 = u.x; v1 = u.y; }
        else if (c < 256)  { float2 u = *(const float2*)&p1[c - 128];  v0 = u.x; v1 = u.y; }
        else if (c < 512)  { float2 u = *(const float2*)&p2[c - 256];  v0 = u.x; v1 = u.y; }
        else if (c < 768)  { float2 u = *(const float2*)&p3[c - 512];  v0 = u.x; v1 = u.y; }
        else if (c < 1280) { float2 u = *(const float2*)&p4[c - 768];  v0 = u.x; v1 = u.y; }
        else if (c < 1792) { v0 = fdec(pg[c - 1280]); v1 = fdec(pg[c - 1279]); }
        else if (c < 1808) { float2 u = *(const float2*)&po[c - 1792]; v0 = u.x; v1 = u.y; }
        ushort2 w; w.x = f2bf(v0); w.y = f2bf(v1);
        *(ushort2*)&fb[c] = w;
        if (c < 1280)                   { *(float2*)&ft[c] = make_float2(v0, v1); }
        else if (c >= 1792 && c < 1808) { *(float2*)&ft[c - 512] = make_float2(v0, v1); }
    }
}

// ---------------------------------------------------------------- launch

extern "C" void kernel_launch(void* const* d_in, const int* in_sizes, int n_in,
                              void* d_out, int out_size, void* d_ws, size_t ws_size,
                              hipStream_t stream) {
    const float* verts  = (const float*)d_in[0];
    const float* onehot = (const float*)d_in[1];
    const float* dir0 = (const float*)d_in[2];
    const float* w1 = (const float*)d_in[3];
    const float* b1 = (const float*)d_in[4];
    const float* dir1 = (const float*)d_in[5];
    const float* w2 = (const float*)d_in[6];
    const float* b2 = (const float*)d_in[7];
    const float* dir2 = (const float*)d_in[8];
    const float* w3 = (const float*)d_in[9];
    const float* b3 = (const float*)d_in[10];
    const float* dir3 = (const float*)d_in[11];
    const float* w4 = (const float*)d_in[12];
    const float* b4 = (const float*)d_in[13];
    const float* dir4 = (const float*)d_in[14];
    const float* g_bn1 = (const float*)d_in[15];
    const float* be_bn1 = (const float*)d_in[16];
    const float* g_bn2 = (const float*)d_in[17];
    const float* be_bn2 = (const float*)d_in[18];
    const float* g_bn3 = (const float*)d_in[19];
    const float* be_bn3 = (const float*)d_in[20];
    const float* wc1 = (const float*)d_in[21];
    const float* bc1 = (const float*)d_in[22];
    const float* wc2 = (const float*)d_in[23];
    const float* bc2 = (const float*)d_in[24];
    const float* wc3 = (const float*)d_in[25];
    const float* bc3 = (const float*)d_in[26];
    float* outf = (float*)d_out;

    float* wsf = (float*)d_ws;
    size_t off = 0;
    auto alloc = [&](size_t n) { float* p = wsf + off; off += (n + 15) & ~(size_t)15; return p; };

    float* sd0 = alloc(3 * 896);
    float* sd1 = alloc(3 * 896);
    float* sd2 = alloc(3 * 1792);
    float* sd3 = alloc(3 * 1792);
    float* sd4 = alloc(3 * 3584);
    float* wc3t = alloc(512L * 30);
    float* fm0 = alloc(8192L * 128);
    float* fm1 = alloc(8192L * 128);
    float* c1  = alloc(8192L * 128);
    float* fm2 = alloc(2048L * 256);
    float* c2  = alloc(2048L * 256);
    float* fm3 = alloc(2048L * 256);
    float* c3  = alloc(2048L * 256);
    float* fm4 = alloc(512L * 512);
    float* statbase = alloc(3328);
    float* stat1 = statbase;
    float* stat2 = statbase + 256;
    float* stat3 = statbase + 768;
    unsigned* fg_enc = (unsigned*)(statbase + 1280);
    float* fbuf = alloc(8192L * 1024);
    float* h2 = alloc(8192L * 512);
    float* pd  = alloc(KTOT);
    ushort* pi = (ushort*)alloc(KTOT / 2);
    int* nb   = (int*)alloc(8192L * KNB);
    int* nb1  = (int*)alloc(2048L * KNB);
    int* nb2  = (int*)alloc(512L * KNB);
    int* nbp1 = (int*)alloc(2048L * 4);
    int* nbp2 = (int*)alloc(512L * 4);
    int* n1   = (int*)alloc(8192);
    int* n2   = (int*)alloc(8192);
    ushort* fuse_b = (ushort*)alloc(8192L * 1824 / 2);
    ushort* h1b    = (ushort*)alloc(8192L * 512 / 2);
    ushort* wc1b   = (ushort*)alloc(512L * 1824 / 2);
    ushort* wc2b   = (ushort*)alloc(512L * 512 / 2);
    ushort* w1tb   = (ushort*)alloc(1024L * 128 / 2);
    ushort* w2tb   = (ushort*)alloc(2048L * 128 / 2);
    ushort* w3tb   = (ushort*)alloc(2048L * 256 / 2);
    ushort* w4tb   = (ushort*)alloc(4096L * 256 / 2);
    ushort* fm0b   = (ushort*)alloc(8192L * 128 / 2);
    ushort* fp1b   = (ushort*)alloc(2048L * 128 / 2);
    ushort* fm2b   = (ushort*)alloc(2048L * 256 / 2);
    ushort* fp2b   = (ushort*)alloc(512L * 256 / 2);

    auto nblk = [](long n, int b) { return (unsigned)((n + b - 1) / b); };

    hipMemsetAsync(statbase, 0, 3328 * sizeof(float), stream);

    // fused front: knn partials + nearest + prep + weight transpose (mutually independent)
    front_uber<<<1088 + PREP_BLOCKS + 1920, 256, 0, stream>>>(
        verts, pd, pi, n1, n2,
        dir0, dir1, dir2, dir3, dir4, sd0, sd1, sd2, sd3, sd4,
        wc3, wc3t, wc1, wc1b, wc2, wc2b,
        w1, w2, w3, w4, w1tb, w2tb, w3tb, w4tb);

    knn_merge_uber<<<2184, 256, 0, stream>>>(pd, pi, nb, nb1, nb2, nbp1, nbp2);

    conv_surface_kernel<<<BSZ * 2048, 128, 0, stream>>>(verts, nb, sd0, fm0, fm0b);

    // layer1 (M=8192, N=1024, K=128)
    gemm_mfma_bt_kernel<<<dim3(8, 64), 256, 0, stream>>>(fm0b, w1tb, b1, fbuf, nullptr, 8192, 1024, 128, 0);
    conv_act_kernel<<<BSZ * 2048, 128, 0, stream>>>(verts, nb, sd1, fbuf, c1, nullptr, 2048, 128);
    bn_stat_kernel<<<256, 256, 0, stream>>>(c1, stat1, 8192, 128);
    bn_apply_relu_kernel<<<nblk(8192L * 128, 256), 256, 0, stream>>>(c1, stat1, g_bn1, be_bn1, fm1, nullptr, 8192, 128);

    pool_b_kernel<<<nblk(BSZ * 512L * 128, 256), 256, 0, stream>>>(fm1, nbp1, fp1b, 2048, 512, 128);

    // layer2 (M=2048, N=2048, K=128)
    gemm_mfma_bt64_kernel<<<dim3(16, 32), 256, 0, stream>>>(fp1b, w2tb, b2, fbuf, nullptr, 2048, 2048, 128, 0);
    conv_act_kernel<<<BSZ * 512, 256, 0, stream>>>(verts, nb1, sd2, fbuf, c2, nullptr, 512, 256);
    bn_stat_kernel<<<256, 256, 0, stream>>>(c2, stat2, 2048, 256);
    bn_apply_relu_kernel<<<nblk(2048L * 256, 256), 256, 0, stream>>>(c2, stat2, g_bn2, be_bn2, fm2, fm2b, 2048, 256);

    // layer3 (M=2048, N=2048, K=256)
    gemm_mfma_bt64_kernel<<<dim3(16, 32), 256, 0, stream>>>(fm2b, w3tb, b3, fbuf, nullptr, 2048, 2048, 256, 0);
    conv_act_kernel<<<BSZ * 512, 256, 0, stream>>>(verts, nb1, sd3, fbuf, c3, nullptr, 512, 256);
    bn_stat_kernel<<<256, 256, 0, stream>>>(c3, stat3, 2048, 256);
    bn_apply_relu_kernel<<<nblk(2048L * 256, 256), 256, 0, stream>>>(c3, stat3, g_bn3, be_bn3, fm3, nullptr, 2048, 256);

    pool_b_kernel<<<nblk(BSZ * 128L * 256, 256), 256, 0, stream>>>(fm3, nbp2, fp2b, 512, 128, 256);

    // layer4 (M=512, N=4096, K=256) -- 64x64 tile: 512 blocks (2/CU)
    gemm_mfma_bt6464_kernel<<<dim3(64, 8), 256, 0, stream>>>(fp2b, w4tb, b4, fbuf, nullptr, 512, 4096, 256, 0);
    conv_act_kernel<<<BSZ * 128, 512, 0, stream>>>(verts, nb2, sd4, fbuf, fm4, fg_enc, 128, 512);

    // fuse -> bf16 GEMM input + fp32 feat (direct to d_out)
    fuse_bf_kernel<<<8192, 256, 0, stream>>>(fm0, fm1, fm2, fm3, fm4, fg_enc, onehot,
                                             n1, n2, fuse_b, outf + 245760);

    // MLP head (M=8192, N=512) -- 64x128 tile + XCD-panel swizzle (CB=4 col-blocks share A panel per XCD)
    gemm_mfma_bt64x_kernel<<<512, 256, 0, stream>>>(fuse_b, wc1b, bc1, nullptr, h1b, 8192, 512, 1824, 1, 4);
    gemm_mfma_bt64x_kernel<<<512, 256, 0, stream>>>(h1b, wc2b, bc2, h2, nullptr, 8192, 512, 512, 1, 4);
    wc3_kernel<<<1024, 256, 0, stream>>>(h2, wc3t, bc3, outf);
}